// Round 11
// baseline (446.146 us; speedup 1.0000x reference)
//
#include <hip/hip_runtime.h>
#include <hip/hip_fp16.h>

#define N_FM 100000
#define N_TP 4096
#define N_SM 100000
#define HID 128
#define E_QOQ 1000000
#define E_BP 1000000
#define E_CP 500000
#define E_CD 500000
#define E_RB 1000000
#define E_TOT 4000000

// global edge-id order: qoq | cp | rb | bp | cd
#define EO_CP  1000000
#define EO_RB  1500000
#define EO_BP  2500000
#define EO_CD  3500000

// element space (concatenated): qoq | cp | rb | bp | cd
#define EL_QOQ 0
#define EL_CP  (N_FM)
#define EL_RB  (2 * N_FM)
#define EL_BP  (3 * N_FM)
#define EL_CD  (3 * N_FM + N_TP)
#define NTOT   (3 * N_FM + N_TP + N_SM)

// buckets: qoq 128 elems (shift 7) | cp/rb/cd 256 (shift 8) | bp 32 (shift 5)
#define BB_QOQ 0
#define BB_CP  782
#define BB_RB  1173
#define BB_BP  1564
#define BB_CD  1692
#define NBUCK  2083
#define CHUNK  4096
#define NCHUNK ((E_TOT + CHUNK - 1) / CHUNK)
#define EPB    (CHUNK / 256)

#define PAIRS_CAP 5784064

// row-kernel grids (must match partial-buffer layout)
#define GRID_FM 768
#define GRID_TP 64
#define GRID_SM 1024

__device__ __forceinline__ int bucket_base(int b) {
    if (b < BB_CP) return b * 2048;
    if (b < BB_RB) return 1601536 + (b - BB_CP) * 2048;
    if (b < BB_BP) return 2402304 + (b - BB_RB) * 3584;
    if (b < BB_CD) return 3803648 + (b - BB_BP) * 9216;
    return 4983296 + (b - BB_CD) * 2048;
}

typedef _Float16 h2 __attribute__((ext_vector_type(2)));
typedef _Float16 f16x8_t __attribute__((ext_vector_type(8)));
typedef float f32x4_t __attribute__((ext_vector_type(4)));

union U32H2 { unsigned u; h2 h; };
union U4H8 { uint4 u; f16x8_t h; };

#if defined(__has_builtin)
#if __has_builtin(__builtin_amdgcn_fdot2)
#define HAVE_FDOT2 1
#endif
#endif

__device__ __forceinline__ unsigned pk2(float a, float b) {
    U32H2 x; x.h = h2{(_Float16)a, (_Float16)b}; return x.u;
}
__device__ __forceinline__ f16x8_t as_h8(uint4 v) { U4H8 x; x.u = v; return x.h; }

// acc += v . sel  (one v_dot2_f32_f16 instead of 2x cvt + 2x add)
__device__ __forceinline__ float dot2sel(float acc, h2 v, h2 sel) {
#ifdef HAVE_FDOT2
    return __builtin_amdgcn_fdot2(v, sel, acc, false);
#else
    return acc + (float)v[0] * (float)sel[0] + (float)v[1] * (float)sel[1];
#endif
}

// ---------------------------------------------------------------- unified pack kernel
// feature sections vectorized float4 (16B/lane)
#define R1 (N_FM * 16)
#define R2 (R1 + N_SM * 8)
#define R3 (R2 + N_TP * 8)
// MFMA-frag-major weights: element j -> f=j>>8 (frag = ks*8+nt), lane=(j>>2)&63, jj=j&3
//   p (h2 pair row) = (f>>3)*16 + ((lane>>4)<<2) + jj ; c = (f&7)*16 + (lane&15)
#define R4 (R3 + 12288)   // fm: 6 ks * 8 nt * 256
#define R5 (R4 + 6144)    // tp: 3 ks * 8 nt * 256
#define R6 (R5 + 4096)    // sm: 2 ks * 8 nt * 256
#define R7 (R6 + 128)     // combined fm bias

__device__ __forceinline__ unsigned pack_pair(const float* W, int p, int c) {
    return pk2(W[(2 * p) * HID + c], W[(2 * p + 1) * HID + c]);
}

__global__ void pack_all(const float* __restrict__ x_fm, const float* __restrict__ x_sm,
                         const float* __restrict__ pe_table, const float* __restrict__ pvol,
                         const float* __restrict__ qoq_Wl, const float* __restrict__ cp_Wl,
                         const float* __restrict__ rb_Wl, const float* __restrict__ qoq_Wr,
                         const float* __restrict__ cp_Wr, const float* __restrict__ rb_Wr,
                         const float* __restrict__ bp_Wl, const float* __restrict__ bp_Wr,
                         const float* __restrict__ cd_Wl, const float* __restrict__ cd_Wr,
                         const float* __restrict__ qoq_bl, const float* __restrict__ cp_bl,
                         const float* __restrict__ rb_bl,
                         unsigned* __restrict__ x_fm_f, unsigned* __restrict__ x_sm_f,
                         unsigned* __restrict__ pe_f, unsigned* __restrict__ wf_fm,
                         unsigned* __restrict__ wf_tp, unsigned* __restrict__ wf_sm,
                         float* __restrict__ bias_fm) {
    int gid = blockIdx.x * blockDim.x + threadIdx.x;
    if (gid < R1) {
        float4 t = ((const float4*)x_fm)[gid];
        uint2 o; o.x = pk2(t.x, t.y); o.y = pk2(t.z, t.w);
        ((uint2*)x_fm_f)[gid] = o;
    } else if (gid < R2) {
        int i = gid - R1;
        float4 t = ((const float4*)x_sm)[i];
        uint2 o; o.x = pk2(t.x, t.y); o.y = pk2(t.z, t.w);
        ((uint2*)x_sm_f)[i] = o;
    } else if (gid < R3) {
        int i = gid - R2;
        float4 t = ((const float4*)pe_table)[i];
        float v = pvol[i >> 3];
        uint2 o; o.x = pk2(t.x * v, t.y * v); o.y = pk2(t.z * v, t.w * v);
        ((uint2*)pe_f)[i] = o;
    } else if (gid < R4) {
        int j = gid - R3;
        int f = j >> 8, lr = (j >> 2) & 63, jj = j & 3;
        int p = (f >> 3) * 16 + ((lr >> 4) << 2) + jj;
        int c = (f & 7) * 16 + (lr & 15);
        unsigned v;
        if (p < 32) v = pack_pair(qoq_Wl, p, c);
        else if (p < 48) v = pack_pair(cp_Wl, p - 32, c);
        else if (p < 64) v = pack_pair(rb_Wl, p - 48, c);
        else {
            int pp = p - 64;
            float u0 = qoq_Wr[(2 * pp) * HID + c] + cp_Wr[(2 * pp) * HID + c] + rb_Wr[(2 * pp) * HID + c];
            float u1 = qoq_Wr[(2 * pp + 1) * HID + c] + cp_Wr[(2 * pp + 1) * HID + c] + rb_Wr[(2 * pp + 1) * HID + c];
            v = pk2(u0, u1);
        }
        wf_fm[j] = v;
    } else if (gid < R5) {
        int j = gid - R4;
        int f = j >> 8, lr = (j >> 2) & 63, jj = j & 3;
        int p = (f >> 3) * 16 + ((lr >> 4) << 2) + jj;
        int c = (f & 7) * 16 + (lr & 15);
        wf_tp[j] = (p < 32) ? pack_pair(bp_Wl, p, c) : pack_pair(bp_Wr, p - 32, c);
    } else if (gid < R6) {
        int j = gid - R5;
        int f = j >> 8, lr = (j >> 2) & 63, jj = j & 3;
        int p = (f >> 3) * 16 + ((lr >> 4) << 2) + jj;
        int c = (f & 7) * 16 + (lr & 15);
        wf_sm[j] = (p < 16) ? pack_pair(cd_Wl, p, c) : pack_pair(cd_Wr, p - 16, c);
    } else if (gid < R7) {
        int c = gid - R6;
        bias_fm[c] = qoq_bl[c] + cp_bl[c] + rb_bl[c];
    }
}

// ---------------------------------------------------------------- edge decode (branchless: selects, then ONE load)
struct EdgePtrs {
    const int *qs, *qd, *cs, *cd_, *rs, *rd, *bs, *bd, *ds, *dd;
};

template <bool NEED_SRC>
__device__ __forceinline__ void edge_decode(const EdgePtrs& P, int e, int& bucket, int& dl, int& src) {
    const int* dp = P.qd; const int* sp = P.qs;
    int i = e, bb = BB_QOQ, sh = 7;
    if (e >= EO_CP) { i = e - EO_CP; dp = P.cd_; sp = P.cs; bb = BB_CP; sh = 8; }
    if (e >= EO_RB) { i = e - EO_RB; dp = P.rd;  sp = P.rs; bb = BB_RB; sh = 8; }
    if (e >= EO_BP) { i = e - EO_BP; dp = P.bd;  sp = P.bs; bb = BB_BP; sh = 5; }
    if (e >= EO_CD) { i = e - EO_CD; dp = P.dd;  sp = P.ds; bb = BB_CD; sh = 8; }
    int d = dp[i];
    bucket = bb + (d >> sh);
    dl = d & ((1 << sh) - 1);
    if (NEED_SRC) src = sp[i];
}

// ---------------------------------------------------------------- bin: block-reserved bucket scatter
// Single decode pass: (bucket|dl, src) cached in registers across both phases.
// Block-reserved bucket slices keep pairs writes CONTIGUOUS per block (write
// amp ~2.2x) -- r8 proved element-ordered direct scatter costs 16x write amp.
// (r10: 64B-padding the bwork counters was NULL -- reverted.)
__global__ void __launch_bounds__(256) bin_kernel(EdgePtrs P, int* __restrict__ bwork,
                                                  unsigned* __restrict__ pairs) {
    __shared__ int lh[NBUCK];
    const int tid = threadIdx.x;
    for (int i = tid; i < NBUCK; i += 256) lh[i] = 0;
    __syncthreads();
    const int base = blockIdx.x * CHUNK;
    const int lim = min(base + CHUNK, E_TOT);
    unsigned ebd[EPB]; int esr[EPB];
#pragma unroll
    for (int j = 0; j < EPB; j++) {
        int e = base + tid + j * 256;
        if (e < lim) {
            int b, dl, s;
            edge_decode<true>(P, e, b, dl, s);
            ebd[j] = ((unsigned)b << 8) | (unsigned)dl;   // b < 4096, dl < 256
            esr[j] = s;
            atomicAdd(&lh[b], 1);
        }
    }
    __syncthreads();
#pragma unroll
    for (int u = 0; u < (NBUCK + 255) / 256; u++) {
        int b = tid + u * 256;
        if (b < NBUCK) {
            int c = lh[b];
            lh[b] = c ? bucket_base(b) + atomicAdd(&bwork[b], c) : 0;
        }
    }
    __syncthreads();
#pragma unroll
    for (int j = 0; j < EPB; j++) {
        int e = base + tid + j * 256;
        if (e < lim) {
            int b = (int)(ebd[j] >> 8);
            int pos = atomicAdd(&lh[b], 1);
            pairs[pos] = ((ebd[j] & 255u) << 24) | (unsigned)esr[j];
        }
    }
}

// ---------------------------------------------------------------- bucket gather (from LDS-sorted list)
// Masked NPRO-slot prologue: ONE (LDS) index stage + ONE fully-parallel feature
// stage covers deg<=NPRO; masked 8-wide continuation for the tail (bp deg~244).
template <int LOGP, int NPRO>
__device__ __forceinline__ void bucket_gather(int ne, size_t gbase, const int* __restrict__ ebeg,
                                              const int* __restrict__ ecnt,
                                              const int* __restrict__ so_lds,
                                              const unsigned* __restrict__ feat,
                                              unsigned* __restrict__ mean, int tid) {
    const int P = 1 << LOGP;
    const int NG = 256 >> LOGP;
    const int grp = tid >> LOGP, fl = tid & (P - 1);
    const h2 SLO = h2{(_Float16)1.0f, (_Float16)0.0f};
    const h2 SHI = h2{(_Float16)0.0f, (_Float16)1.0f};
    for (int dl = grp; dl < ne; dl += NG) {
        int bgl = ebeg[dl], n = ecnt[dl];
        float alo = 0.0f, ahi = 0.0f;
        if (n > 0) {
            const int nm1 = n - 1;
            int s[NPRO];
#pragma unroll
            for (int j = 0; j < NPRO; j++) s[j] = so_lds[bgl + min(j, nm1)];
            unsigned v[NPRO];
#pragma unroll
            for (int j = 0; j < NPRO; j++) v[j] = feat[(size_t)(unsigned)s[j] * P + fl];
#pragma unroll
            for (int j = 0; j < NPRO; j++) {
                U32H2 u; u.u = (j < n) ? v[j] : 0u;
                alo = dot2sel(alo, u.h, SLO); ahi = dot2sel(ahi, u.h, SHI);
            }
            for (int i = NPRO; i < n; i += 8) {
                int t_[8]; unsigned w_[8];
#pragma unroll
                for (int j = 0; j < 8; j++) t_[j] = so_lds[bgl + min(i + j, nm1)];
#pragma unroll
                for (int j = 0; j < 8; j++) w_[j] = feat[(size_t)(unsigned)t_[j] * P + fl];
#pragma unroll
                for (int j = 0; j < 8; j++) {
                    U32H2 u; u.u = (i + j < n) ? w_[j] : 0u;
                    alo = dot2sel(alo, u.h, SLO); ahi = dot2sel(ahi, u.h, SHI);
                }
            }
        }
        float ic = (n > 0) ? 1.0f / (float)n : 0.0f;
        mean[(gbase + (size_t)dl) * P + fl] = pk2(alo * ic, ahi * ic);
    }
}

// ---------------------------------------------------------------- esga: fused esort + gather
// Counting sort stays entirely in LDS (so_lds), gather reads it directly --
// eliminates the 38MB so_all/el_beg/el_end HBM round-trip and one launch.
__global__ void __launch_bounds__(256)
esga(const int* __restrict__ bwork, const unsigned* __restrict__ pairs,
     const unsigned* __restrict__ x_fm_f, const unsigned* __restrict__ pe_f,
     unsigned* __restrict__ mean_qoq, unsigned* __restrict__ mean_cp,
     unsigned* __restrict__ mean_rb, unsigned* __restrict__ mean_bp,
     unsigned* __restrict__ mean_cd) {
    __shared__ int hist[256];
    __shared__ int wsum[4];
    __shared__ int ebeg[256];
    __shared__ int ecnt[256];
    __shared__ int so_lds[9216];  // max bucket capacity (bp)
    const int b = blockIdx.x, tid = threadIdx.x;
    const int lane = tid & 63, wv = tid >> 6;
    int beg = bucket_base(b);
    int end = beg + bwork[b];
    int e0, ne, cls;
    if (b < BB_CP)      { e0 = (b - BB_QOQ) << 7; ne = min(128, N_FM - e0); cls = 0; }
    else if (b < BB_RB) { e0 = (b - BB_CP) << 8;  ne = min(256, N_FM - e0); cls = 1; }
    else if (b < BB_BP) { e0 = (b - BB_RB) << 8;  ne = min(256, N_FM - e0); cls = 2; }
    else if (b < BB_CD) { e0 = (b - BB_BP) << 5;  ne = min(32, N_TP - e0);  cls = 3; }
    else                { e0 = (b - BB_CD) << 8;  ne = min(256, N_SM - e0); cls = 4; }
    hist[tid] = 0;
    __syncthreads();
    for (int e = beg + tid; e < end; e += 256)
        atomicAdd(&hist[pairs[e] >> 24], 1);
    __syncthreads();
    int v = hist[tid];
    // inclusive wave scan (r9-verified)
    int x = v;
#pragma unroll
    for (int off = 1; off < 64; off <<= 1) {
        int u = __shfl_up(x, off);
        if (lane >= off) x += u;
    }
    if (lane == 63) wsum[wv] = x;
    __syncthreads();
    int wbase = 0;
#pragma unroll
    for (int w = 0; w < 4; w++) wbase += (w < wv) ? wsum[w] : 0;
    int excl = wbase + x - v;
    ebeg[tid] = excl;
    ecnt[tid] = v;
    hist[tid] = excl;  // bucket-relative cursor
    __syncthreads();
    for (int e = beg + tid; e < end; e += 256) {
        unsigned pr = pairs[e];
        int dl = pr >> 24;
        int pos = atomicAdd(&hist[dl], 1);
        so_lds[pos] = (int)(pr & 0xFFFFFF);
    }
    __syncthreads();
    if (cls == 0)      bucket_gather<5, 16>(ne, (size_t)e0, ebeg, ecnt, so_lds, x_fm_f, mean_qoq, tid);
    else if (cls == 1) bucket_gather<4, 8>(ne, (size_t)e0, ebeg, ecnt, so_lds, pe_f, mean_cp, tid);
    else if (cls == 2) bucket_gather<4, 16>(ne, (size_t)e0, ebeg, ecnt, so_lds, pe_f, mean_rb, tid);
    else if (cls == 3) bucket_gather<5, 16>(ne, (size_t)e0, ebeg, ecnt, so_lds, x_fm_f, mean_bp, tid);
    else               bucket_gather<4, 8>(ne, (size_t)e0, ebeg, ecnt, so_lds, pe_f, mean_cd, tid);
}

// ---------------------------------------------------------------- MFMA row kernels
// A-frag (16x32 f16): lane holds row=(lane&15), k=(lane>>4)*8..+7 -> contiguous uint4 at
//   u32 off = ks*16 + (lane>>4)*4 within the row. B-frag staged in LDS frag-major.
// C-frag: col=lane&15, row=(lane>>4)*4+reg  [verified layout, learn_hip m89]
// Column sums: block-level LDS reduce -> one 128-float partial per block (NO atomics).

__global__ void __launch_bounds__(256)
fm_mfma(const unsigned* __restrict__ mq, const unsigned* __restrict__ mc,
        const unsigned* __restrict__ mr, const unsigned* __restrict__ xf,
        const unsigned* __restrict__ wfrag, const float* __restrict__ bias,
        const float* __restrict__ ln_g, const float* __restrict__ ln_b,
        float* __restrict__ part) {
    __shared__ uint4 wlds[48 * 64];  // 48 KB
    const int tid = threadIdx.x, lane = tid & 63, wid = tid >> 6;
    for (int i = tid; i < 48 * 64; i += 256) wlds[i] = ((const uint4*)wfrag)[i];
    const int c0 = lane & 15, ko = lane >> 4;
    float bias_[8], g_[8], b_[8], colacc[8];
#pragma unroll
    for (int nt = 0; nt < 8; nt++) {
        int c = nt * 16 + c0;
        bias_[nt] = bias[c]; g_[nt] = ln_g[c]; b_[nt] = ln_b[c]; colacc[nt] = 0.0f;
    }
    __syncthreads();
    const f32x4_t zero = {0.0f, 0.0f, 0.0f, 0.0f};
    const int ntiles = N_FM / 16;
    for (int tile = blockIdx.x * 4 + wid; tile < ntiles; tile += gridDim.x * 4) {
        const size_t row = (size_t)tile * 16 + c0;
        uint4 av[6];
        av[0] = ((const uint4*)mq)[row * 8 + ko];
        av[1] = ((const uint4*)mq)[row * 8 + 4 + ko];
        av[2] = ((const uint4*)mc)[row * 4 + ko];
        av[3] = ((const uint4*)mr)[row * 4 + ko];
        av[4] = ((const uint4*)xf)[row * 8 + ko];
        av[5] = ((const uint4*)xf)[row * 8 + 4 + ko];
        f32x4_t acc[8];
#pragma unroll
        for (int nt = 0; nt < 8; nt++) acc[nt] = zero;
#pragma unroll
        for (int ks = 0; ks < 6; ks++) {
            f16x8_t af = as_h8(av[ks]);
#pragma unroll
            for (int nt = 0; nt < 8; nt++)
                acc[nt] = __builtin_amdgcn_mfma_f32_16x16x32_f16(
                    af, as_h8(wlds[(ks * 8 + nt) * 64 + lane]), acc[nt], 0, 0, 0);
        }
#pragma unroll
        for (int r = 0; r < 4; r++) {
            float yv[8]; float s = 0.0f, q = 0.0f;
#pragma unroll
            for (int nt = 0; nt < 8; nt++) {
                float y = (acc[nt][r] + bias_[nt]) * (1.0f / 3.0f);
                yv[nt] = y; s += y; q += y * y;
            }
#pragma unroll
            for (int off = 1; off < 16; off <<= 1) { s += __shfl_xor(s, off); q += __shfl_xor(q, off); }
            float mu = s * (1.0f / 128.0f);
            float var = fmaxf(q * (1.0f / 128.0f) - mu * mu, 0.0f);
            float rs = rsqrtf(var + 1e-5f);
#pragma unroll
            for (int nt = 0; nt < 8; nt++)
                colacc[nt] += fmaxf((yv[nt] - mu) * rs * g_[nt] + b_[nt], 0.0f);
        }
    }
#pragma unroll
    for (int nt = 0; nt < 8; nt++) {
        colacc[nt] += __shfl_xor(colacc[nt], 16);
        colacc[nt] += __shfl_xor(colacc[nt], 32);
    }
    __syncthreads();  // all waves done with wlds; reuse as reduction scratch
    float* sred = (float*)wlds;
    if (lane < 16) {
#pragma unroll
        for (int nt = 0; nt < 8; nt++) sred[wid * 128 + nt * 16 + lane] = colacc[nt];
    }
    __syncthreads();
    if (tid < 128)
        part[(size_t)blockIdx.x * 128 + tid] =
            sred[tid] + sred[128 + tid] + sred[256 + tid] + sred[384 + tid];
}

template <int KSA, int KSB>
__global__ void __launch_bounds__(256)
rows_mfma(int ntiles, const unsigned* __restrict__ mA, const unsigned* __restrict__ xB,
          const unsigned* __restrict__ wfrag, const float* __restrict__ bl,
          const float* __restrict__ ln_g, const float* __restrict__ ln_b,
          float* __restrict__ part) {
    constexpr int KS = KSA + KSB;
    __shared__ uint4 wlds[KS * 8 * 64];
    const int tid = threadIdx.x, lane = tid & 63, wid = tid >> 6;
    for (int i = tid; i < KS * 8 * 64; i += 256) wlds[i] = ((const uint4*)wfrag)[i];
    const int c0 = lane & 15, ko = lane >> 4;
    float bias_[8], g_[8], b_[8], colacc[8];
#pragma unroll
    for (int nt = 0; nt < 8; nt++) {
        int c = nt * 16 + c0;
        bias_[nt] = bl[c]; g_[nt] = ln_g[c]; b_[nt] = ln_b[c]; colacc[nt] = 0.0f;
    }
    __syncthreads();
    const f32x4_t zero = {0.0f, 0.0f, 0.0f, 0.0f};
    for (int tile = blockIdx.x * 4 + wid; tile < ntiles; tile += gridDim.x * 4) {
        const size_t row = (size_t)tile * 16 + c0;
        uint4 av[KS];
#pragma unroll
        for (int ks = 0; ks < KSA; ks++) av[ks] = ((const uint4*)mA)[row * (KSA * 4) + ks * 4 + ko];
#pragma unroll
        for (int ks = 0; ks < KSB; ks++) av[KSA + ks] = ((const uint4*)xB)[row * (KSB * 4) + ks * 4 + ko];
        f32x4_t acc[8];
#pragma unroll
        for (int nt = 0; nt < 8; nt++) acc[nt] = zero;
#pragma unroll
        for (int ks = 0; ks < KS; ks++) {
            f16x8_t af = as_h8(av[ks]);
#pragma unroll
            for (int nt = 0; nt < 8; nt++)
                acc[nt] = __builtin_amdgcn_mfma_f32_16x16x32_f16(
                    af, as_h8(wlds[(ks * 8 + nt) * 64 + lane]), acc[nt], 0, 0, 0);
        }
#pragma unroll
        for (int r = 0; r < 4; r++) {
            float yv[8]; float s = 0.0f, q = 0.0f;
#pragma unroll
            for (int nt = 0; nt < 8; nt++) {
                float y = acc[nt][r] + bias_[nt];
                yv[nt] = y; s += y; q += y * y;
            }
#pragma unroll
            for (int off = 1; off < 16; off <<= 1) { s += __shfl_xor(s, off); q += __shfl_xor(q, off); }
            float mu = s * (1.0f / 128.0f);
            float var = fmaxf(q * (1.0f / 128.0f) - mu * mu, 0.0f);
            float rs = rsqrtf(var + 1e-5f);
#pragma unroll
            for (int nt = 0; nt < 8; nt++)
                colacc[nt] += fmaxf((yv[nt] - mu) * rs * g_[nt] + b_[nt], 0.0f);
        }
    }
#pragma unroll
    for (int nt = 0; nt < 8; nt++) {
        colacc[nt] += __shfl_xor(colacc[nt], 16);
        colacc[nt] += __shfl_xor(colacc[nt], 32);
    }
    __syncthreads();  // all waves done with wlds; reuse as reduction scratch
    float* sred = (float*)wlds;
    if (lane < 16) {
#pragma unroll
        for (int nt = 0; nt < 8; nt++) sred[wid * 128 + nt * 16 + lane] = colacc[nt];
    }
    __syncthreads();
    if (tid < 128)
        part[(size_t)blockIdx.x * 128 + tid] =
            sred[tid] + sred[128 + tid] + sred[256 + tid] + sred[384 + tid];
}

// ---------------------------------------------------------------- partial-sum reduction (replaces atomics)
__global__ void __launch_bounds__(512)
reduce_cols(const float* __restrict__ part, float* __restrict__ colsum) {
    __shared__ float lds[512];
    const int t = threadIdx.x, col = t & 127, sl = t >> 7;
    int cnt, srcoff, dst;
    if (blockIdx.x == 0)      { cnt = GRID_FM; srcoff = 0;                         dst = 0;   }
    else if (blockIdx.x == 1) { cnt = GRID_TP; srcoff = GRID_FM * 128;             dst = 128; }
    else                      { cnt = GRID_SM; srcoff = (GRID_FM + GRID_TP) * 128; dst = 256; }
    float a = 0.0f;
    for (int i = sl; i < cnt; i += 4) a += part[srcoff + i * 128 + col];
    lds[t] = a;
    __syncthreads();
    if (t < 128) colsum[dst + t] = lds[t] + lds[128 + t] + lds[256 + t] + lds[384 + t];
}

// ---------------------------------------------------------------- head MLP -> scalar (split-K)
__global__ void head_kernel(const float* __restrict__ colsum, const float* __restrict__ gf,
                            const float* __restrict__ W1, const float* __restrict__ b1,
                            const float* __restrict__ W2, const float* __restrict__ b2,
                            float* __restrict__ out) {
    __shared__ float h[448];
    __shared__ float sh[512];
    __shared__ float h1[64];
    int t = threadIdx.x;  // 512 threads
    if (t < 128) h[t] = colsum[t] * (1.0f / N_FM);
    else if (t < 256) h[t] = colsum[t] * (1.0f / N_TP);
    else if (t < 384) h[t] = colsum[t] * (1.0f / N_SM);
    else if (t < 448) h[t] = gf[t - 384];
    __syncthreads();
    {
        int col = t & 63, slice = t >> 6;
        float a = 0.0f;
        for (int k = slice * 56; k < slice * 56 + 56; k++) a += h[k] * W1[k * 64 + col];
        sh[slice * 64 + col] = a;
    }
    __syncthreads();
    if (t < 64) {
        float a = b1[t];
#pragma unroll
        for (int s = 0; s < 8; s++) a += sh[s * 64 + t];
        h1[t] = fmaxf(a, 0.0f);
    }
    __syncthreads();
    if (t < 64) {
        float p = h1[t] * W2[t];
#pragma unroll
        for (int off = 1; off < 64; off <<= 1) p += __shfl_xor(p, off);
        if (t == 0) out[0] = p + b2[0];
    }
}

extern "C" void kernel_launch(void* const* d_in, const int* in_sizes, int n_in,
                              void* d_out, int out_size, void* d_ws, size_t ws_size,
                              hipStream_t stream) {
    const float* x_fm = (const float*)d_in[0];
    const float* x_sm = (const float*)d_in[1];
    const float* period_vol = (const float*)d_in[2];
    const float* gf = (const float*)d_in[3];
    const float* pe_table = (const float*)d_in[4];
    const int* qoq_src = (const int*)d_in[5];
    const int* qoq_dst = (const int*)d_in[6];
    const int* bp_src = (const int*)d_in[7];
    const int* bp_dst = (const int*)d_in[8];
    const int* cp_src = (const int*)d_in[9];
    const int* cp_dst = (const int*)d_in[10];
    const int* cd_src = (const int*)d_in[11];
    const int* cd_dst = (const int*)d_in[12];
    const int* rb_src = (const int*)d_in[13];
    const int* rb_dst = (const int*)d_in[14];
    const float* qoq_Wl = (const float*)d_in[15];
    const float* qoq_bl = (const float*)d_in[16];
    const float* qoq_Wr = (const float*)d_in[17];
    const float* bp_Wl = (const float*)d_in[18];
    const float* bp_bl = (const float*)d_in[19];
    const float* bp_Wr = (const float*)d_in[20];
    const float* cp_Wl = (const float*)d_in[21];
    const float* cp_bl = (const float*)d_in[22];
    const float* cp_Wr = (const float*)d_in[23];
    const float* cd_Wl = (const float*)d_in[24];
    const float* cd_bl = (const float*)d_in[25];
    const float* cd_Wr = (const float*)d_in[26];
    const float* rb_Wl = (const float*)d_in[27];
    const float* rb_bl = (const float*)d_in[28];
    const float* rb_Wr = (const float*)d_in[29];
    const float* ln_fm_g = (const float*)d_in[30];
    const float* ln_fm_b = (const float*)d_in[31];
    const float* ln_tp_g = (const float*)d_in[32];
    const float* ln_tp_b = (const float*)d_in[33];
    const float* ln_sm_g = (const float*)d_in[34];
    const float* ln_sm_b = (const float*)d_in[35];
    const float* head_W1 = (const float*)d_in[36];
    const float* head_b1 = (const float*)d_in[37];
    const float* head_W2 = (const float*)d_in[38];
    const float* head_b2 = (const float*)d_in[39];

    // workspace (4-byte words); zero region: bucket cursors + colsum
    unsigned* wsu = (unsigned*)d_ws;
    size_t off = 0;
    int* bwork = (int*)(wsu + off); off += NBUCK;
    float* colsum = (float*)(wsu + off); off += 384;
    size_t zero_words = off;
    off = (off + 3) & ~(size_t)3;  // 16B-align everything downstream (uint4 loads)
    unsigned* pairs = wsu + off; off += PAIRS_CAP;
    unsigned* mean_qoq = wsu + off; off += (size_t)N_FM * 32;
    unsigned* mean_cp  = wsu + off; off += (size_t)N_FM * 16;
    unsigned* mean_rb  = wsu + off; off += (size_t)N_FM * 16;
    unsigned* mean_bp  = wsu + off; off += (size_t)N_TP * 32;
    unsigned* mean_cd  = wsu + off; off += (size_t)N_SM * 16;
    unsigned* pe_f     = wsu + off; off += (size_t)N_TP * 16;
    unsigned* x_fm_f   = wsu + off; off += (size_t)N_FM * 32;
    unsigned* x_sm_f   = wsu + off; off += (size_t)N_SM * 16;
    unsigned* wf_fm    = wsu + off; off += 12288;
    unsigned* wf_tp    = wsu + off; off += 6144;
    unsigned* wf_sm    = wsu + off; off += 4096;
    float* bias_fm     = (float*)(wsu + off); off += 128;

    // per-block column partials alias the (dead-after-esga) pairs buffer
    float* part_fm = (float*)pairs;                 // GRID_FM*128
    float* part_tp = part_fm + GRID_FM * 128;       // GRID_TP*128
    float* part_sm = part_tp + GRID_TP * 128;       // GRID_SM*128

    hipMemsetAsync(d_ws, 0, zero_words * 4, stream);

    pack_all<<<(R7 + 255) / 256, 256, 0, stream>>>(
        x_fm, x_sm, pe_table, period_vol, qoq_Wl, cp_Wl, rb_Wl, qoq_Wr, cp_Wr, rb_Wr,
        bp_Wl, bp_Wr, cd_Wl, cd_Wr, qoq_bl, cp_bl, rb_bl,
        x_fm_f, x_sm_f, pe_f, wf_fm, wf_tp, wf_sm, bias_fm);

    EdgePtrs EP{qoq_src, qoq_dst, cp_src, cp_dst, rb_src, rb_dst, bp_src, bp_dst, cd_src, cd_dst};

    bin_kernel<<<NCHUNK, 256, 0, stream>>>(EP, bwork, pairs);
    esga<<<NBUCK, 256, 0, stream>>>(bwork, pairs, x_fm_f, pe_f,
                                    mean_qoq, mean_cp, mean_rb, mean_bp, mean_cd);

    // MFMA row kernels (fused GEMM + LN + ReLU + per-block column partials)
    fm_mfma<<<GRID_FM, 256, 0, stream>>>(mean_qoq, mean_cp, mean_rb, x_fm_f, wf_fm,
                                         bias_fm, ln_fm_g, ln_fm_b, part_fm);
    rows_mfma<2, 1><<<GRID_TP, 256, 0, stream>>>(N_TP / 16, mean_bp, pe_f, wf_tp,
                                                 bp_bl, ln_tp_g, ln_tp_b, part_tp);
    rows_mfma<1, 1><<<GRID_SM, 256, 0, stream>>>(N_SM / 16, mean_cd, x_sm_f, wf_sm,
                                                 cd_bl, ln_sm_g, ln_sm_b, part_sm);

    reduce_cols<<<3, 512, 0, stream>>>(part_fm, colsum);

    head_kernel<<<1, 512, 0, stream>>>(colsum, gf, head_W1, head_b1, head_W2, head_b2,
                                       (float*)d_out);
}

// Round 12
// 445.947 us; speedup vs baseline: 1.0004x; 1.0004x over previous
//
#include <hip/hip_runtime.h>
#include <hip/hip_fp16.h>

#define N_FM 100000
#define N_TP 4096
#define N_SM 100000
#define HID 128
#define E_QOQ 1000000
#define E_BP 1000000
#define E_CP 500000
#define E_CD 500000
#define E_RB 1000000
#define E_TOT 4000000

// global edge-id order: qoq | cp | rb | bp | cd
#define EO_CP  1000000
#define EO_RB  1500000
#define EO_BP  2500000
#define EO_CD  3500000

// element space (concatenated): qoq | cp | rb | bp | cd
#define EL_QOQ 0
#define EL_CP  (N_FM)
#define EL_RB  (2 * N_FM)
#define EL_BP  (3 * N_FM)
#define EL_CD  (3 * N_FM + N_TP)
#define NTOT   (3 * N_FM + N_TP + N_SM)

// buckets: qoq 128 elems (shift 7) | cp/rb/cd 256 (shift 8) | bp 32 (shift 5)
#define BB_QOQ 0
#define BB_CP  782
#define BB_RB  1173
#define BB_BP  1564
#define BB_CD  1692
#define NBUCK  2083
#define CHUNK  4096
#define NCHUNK ((E_TOT + CHUNK - 1) / CHUNK)
#define EPB    (CHUNK / 256)

#define PAIRS_CAP 5784064

// row-kernel grids (must match partial-buffer layout)
#define GRID_FM 768
#define GRID_TP 64
#define GRID_SM 1024

__device__ __forceinline__ int bucket_base(int b) {
    if (b < BB_CP) return b * 2048;
    if (b < BB_RB) return 1601536 + (b - BB_CP) * 2048;
    if (b < BB_BP) return 2402304 + (b - BB_RB) * 3584;
    if (b < BB_CD) return 3803648 + (b - BB_BP) * 9216;
    return 4983296 + (b - BB_CD) * 2048;
}

typedef _Float16 h2 __attribute__((ext_vector_type(2)));
typedef _Float16 f16x8_t __attribute__((ext_vector_type(8)));
typedef float f32x4_t __attribute__((ext_vector_type(4)));

union U32H2 { unsigned u; h2 h; };
union U4H8 { uint4 u; f16x8_t h; };

#if defined(__has_builtin)
#if __has_builtin(__builtin_amdgcn_fdot2)
#define HAVE_FDOT2 1
#endif
#endif

__device__ __forceinline__ unsigned pk2(float a, float b) {
    U32H2 x; x.h = h2{(_Float16)a, (_Float16)b}; return x.u;
}
__device__ __forceinline__ f16x8_t as_h8(uint4 v) { U4H8 x; x.u = v; return x.h; }

// acc += v . sel  (one v_dot2_f32_f16 instead of 2x cvt + 2x add)
__device__ __forceinline__ float dot2sel(float acc, h2 v, h2 sel) {
#ifdef HAVE_FDOT2
    return __builtin_amdgcn_fdot2(v, sel, acc, false);
#else
    return acc + (float)v[0] * (float)sel[0] + (float)v[1] * (float)sel[1];
#endif
}

// ---------------------------------------------------------------- pack work (runs as extra blocks of bin_pack)
// feature sections vectorized float4 (16B/lane)
#define R1 (N_FM * 16)
#define R2 (R1 + N_SM * 8)
#define R3 (R2 + N_TP * 8)
// MFMA-frag-major weights: element j -> f=j>>8 (frag = ks*8+nt), lane=(j>>2)&63, jj=j&3
//   p (h2 pair row) = (f>>3)*16 + ((lane>>4)<<2) + jj ; c = (f&7)*16 + (lane&15)
#define R4 (R3 + 12288)   // fm: 6 ks * 8 nt * 256
#define R5 (R4 + 6144)    // tp: 3 ks * 8 nt * 256
#define R6 (R5 + 4096)    // sm: 2 ks * 8 nt * 256
#define R7 (R6 + 128)     // combined fm bias
#define PACK_BLOCKS ((R7 + 255) / 256)

struct PackPtrs {
    const float *x_fm, *x_sm, *pe_table, *pvol;
    const float *qoq_Wl, *cp_Wl, *rb_Wl, *qoq_Wr, *cp_Wr, *rb_Wr;
    const float *bp_Wl, *bp_Wr, *cd_Wl, *cd_Wr;
    const float *qoq_bl, *cp_bl, *rb_bl;
    unsigned *x_fm_f, *x_sm_f, *pe_f, *wf_fm, *wf_tp, *wf_sm;
    float *bias_fm;
};

__device__ __forceinline__ unsigned pack_pair(const float* W, int p, int c) {
    return pk2(W[(2 * p) * HID + c], W[(2 * p + 1) * HID + c]);
}

__device__ __forceinline__ void pack_body(const PackPtrs& K, int gid) {
    if (gid < R1) {
        float4 t = ((const float4*)K.x_fm)[gid];
        uint2 o; o.x = pk2(t.x, t.y); o.y = pk2(t.z, t.w);
        ((uint2*)K.x_fm_f)[gid] = o;
    } else if (gid < R2) {
        int i = gid - R1;
        float4 t = ((const float4*)K.x_sm)[i];
        uint2 o; o.x = pk2(t.x, t.y); o.y = pk2(t.z, t.w);
        ((uint2*)K.x_sm_f)[i] = o;
    } else if (gid < R3) {
        int i = gid - R2;
        float4 t = ((const float4*)K.pe_table)[i];
        float v = K.pvol[i >> 3];
        uint2 o; o.x = pk2(t.x * v, t.y * v); o.y = pk2(t.z * v, t.w * v);
        ((uint2*)K.pe_f)[i] = o;
    } else if (gid < R4) {
        int j = gid - R3;
        int f = j >> 8, lr = (j >> 2) & 63, jj = j & 3;
        int p = (f >> 3) * 16 + ((lr >> 4) << 2) + jj;
        int c = (f & 7) * 16 + (lr & 15);
        unsigned v;
        if (p < 32) v = pack_pair(K.qoq_Wl, p, c);
        else if (p < 48) v = pack_pair(K.cp_Wl, p - 32, c);
        else if (p < 64) v = pack_pair(K.rb_Wl, p - 48, c);
        else {
            int pp = p - 64;
            float u0 = K.qoq_Wr[(2 * pp) * HID + c] + K.cp_Wr[(2 * pp) * HID + c] + K.rb_Wr[(2 * pp) * HID + c];
            float u1 = K.qoq_Wr[(2 * pp + 1) * HID + c] + K.cp_Wr[(2 * pp + 1) * HID + c] + K.rb_Wr[(2 * pp + 1) * HID + c];
            v = pk2(u0, u1);
        }
        K.wf_fm[j] = v;
    } else if (gid < R5) {
        int j = gid - R4;
        int f = j >> 8, lr = (j >> 2) & 63, jj = j & 3;
        int p = (f >> 3) * 16 + ((lr >> 4) << 2) + jj;
        int c = (f & 7) * 16 + (lr & 15);
        K.wf_tp[j] = (p < 32) ? pack_pair(K.bp_Wl, p, c) : pack_pair(K.bp_Wr, p - 32, c);
    } else if (gid < R6) {
        int j = gid - R5;
        int f = j >> 8, lr = (j >> 2) & 63, jj = j & 3;
        int p = (f >> 3) * 16 + ((lr >> 4) << 2) + jj;
        int c = (f & 7) * 16 + (lr & 15);
        K.wf_sm[j] = (p < 16) ? pack_pair(K.cd_Wl, p, c) : pack_pair(K.cd_Wr, p - 16, c);
    } else if (gid < R7) {
        int c = gid - R6;
        K.bias_fm[c] = K.qoq_bl[c] + K.cp_bl[c] + K.rb_bl[c];
    }
}

// ---------------------------------------------------------------- edge decode (branchless: selects, then ONE load)
struct EdgePtrs {
    const int *qs, *qd, *cs, *cd_, *rs, *rd, *bs, *bd, *ds, *dd;
};

template <bool NEED_SRC>
__device__ __forceinline__ void edge_decode(const EdgePtrs& P, int e, int& bucket, int& dl, int& src) {
    const int* dp = P.qd; const int* sp = P.qs;
    int i = e, bb = BB_QOQ, sh = 7;
    if (e >= EO_CP) { i = e - EO_CP; dp = P.cd_; sp = P.cs; bb = BB_CP; sh = 8; }
    if (e >= EO_RB) { i = e - EO_RB; dp = P.rd;  sp = P.rs; bb = BB_RB; sh = 8; }
    if (e >= EO_BP) { i = e - EO_BP; dp = P.bd;  sp = P.bs; bb = BB_BP; sh = 5; }
    if (e >= EO_CD) { i = e - EO_CD; dp = P.dd;  sp = P.ds; bb = BB_CD; sh = 8; }
    int d = dp[i];
    bucket = bb + (d >> sh);
    dl = d & ((1 << sh) - 1);
    if (NEED_SRC) src = sp[i];
}

// ---------------------------------------------------------------- bin_pack: bucket scatter + (fused) pack blocks
// Blocks [0,NCHUNK): bin -- single decode pass, (bucket|dl,src) reg-cached,
// block-reserved bucket slices keep pairs writes contiguous (r8: element-
// ordered scatter costs 16x write amp). Blocks [NCHUNK,..): pack_all body --
// independent streaming work that previously serialized ~15-20us before bin;
// now overlaps bin's latency-bound phases.
__global__ void __launch_bounds__(256) bin_pack(EdgePtrs P, PackPtrs K, int* __restrict__ bwork,
                                                unsigned* __restrict__ pairs) {
    __shared__ int lh[NBUCK];
    const int tid = threadIdx.x;
    if (blockIdx.x >= NCHUNK) {
        pack_body(K, (int)(blockIdx.x - NCHUNK) * 256 + tid);
        return;
    }
    for (int i = tid; i < NBUCK; i += 256) lh[i] = 0;
    __syncthreads();
    const int base = blockIdx.x * CHUNK;
    const int lim = min(base + CHUNK, E_TOT);
    unsigned ebd[EPB]; int esr[EPB];
#pragma unroll
    for (int j = 0; j < EPB; j++) {
        int e = base + tid + j * 256;
        if (e < lim) {
            int b, dl, s;
            edge_decode<true>(P, e, b, dl, s);
            ebd[j] = ((unsigned)b << 8) | (unsigned)dl;   // b < 4096, dl < 256
            esr[j] = s;
            atomicAdd(&lh[b], 1);
        }
    }
    __syncthreads();
#pragma unroll
    for (int u = 0; u < (NBUCK + 255) / 256; u++) {
        int b = tid + u * 256;
        if (b < NBUCK) {
            int c = lh[b];
            lh[b] = c ? bucket_base(b) + atomicAdd(&bwork[b], c) : 0;
        }
    }
    __syncthreads();
#pragma unroll
    for (int j = 0; j < EPB; j++) {
        int e = base + tid + j * 256;
        if (e < lim) {
            int b = (int)(ebd[j] >> 8);
            int pos = atomicAdd(&lh[b], 1);
            pairs[pos] = ((ebd[j] & 255u) << 24) | (unsigned)esr[j];
        }
    }
}

// ---------------------------------------------------------------- esort: per-bucket LDS counting sort by element
// Wave-shuffle scan (6 shfl steps + 2 barriers).
__global__ void __launch_bounds__(256) esort(const int* __restrict__ bwork,
                                             const unsigned* __restrict__ pairs,
                                             int* __restrict__ so,
                                             int* __restrict__ el_beg, int* __restrict__ el_end) {
    __shared__ int hist[256];
    __shared__ int wsum[4];
    __shared__ int so_lds[9216];  // max bucket capacity (bp)
    const int b = blockIdx.x;
    const int tid = threadIdx.x;
    const int lane = tid & 63, wv = tid >> 6;
    int beg = bucket_base(b);
    int end = beg + bwork[b];
    int egbase, ne;
    if (b < BB_CP)      { int e0 = (b - BB_QOQ) << 7; egbase = EL_QOQ + e0; ne = min(128, N_FM - e0); }
    else if (b < BB_RB) { int e0 = (b - BB_CP) << 8;  egbase = EL_CP + e0;  ne = min(256, N_FM - e0); }
    else if (b < BB_BP) { int e0 = (b - BB_RB) << 8;  egbase = EL_RB + e0;  ne = min(256, N_FM - e0); }
    else if (b < BB_CD) { int e0 = (b - BB_BP) << 5;  egbase = EL_BP + e0;  ne = min(32, N_TP - e0); }
    else                { int e0 = (b - BB_CD) << 8;  egbase = EL_CD + e0;  ne = min(256, N_SM - e0); }
    hist[tid] = 0;
    __syncthreads();
    for (int e = beg + tid; e < end; e += 256)
        atomicAdd(&hist[pairs[e] >> 24], 1);
    __syncthreads();
    int v = hist[tid];
    // inclusive wave scan
    int x = v;
#pragma unroll
    for (int off = 1; off < 64; off <<= 1) {
        int u = __shfl_up(x, off);
        if (lane >= off) x += u;
    }
    if (lane == 63) wsum[wv] = x;
    __syncthreads();
    int wbase = 0;
#pragma unroll
    for (int w = 0; w < 4; w++) wbase += (w < wv) ? wsum[w] : 0;
    int excl = wbase + x - v;
    if (tid < ne) {
        el_beg[egbase + tid] = beg + excl;
        el_end[egbase + tid] = beg + excl + v;
    }
    hist[tid] = excl;  // bucket-relative cursor
    __syncthreads();
    for (int e = beg + tid; e < end; e += 256) {
        unsigned pr = pairs[e];
        int dl = pr >> 24;
        int pos = atomicAdd(&hist[dl], 1);
        so_lds[pos] = (int)(pr & 0xFFFFFF);
    }
    __syncthreads();
    const int n = end - beg;
    for (int i = tid; i < n; i += 256) so[beg + i] = so_lds[i];
}

// ---------------------------------------------------------------- gather: element CSR, register fp32 accumulate
// Masked NPRO-slot prologue: ONE index stage + ONE fully-parallel feature stage
// covers deg<=NPRO (avg deg 10 / 5); overflow uses 8-deep continuation.
template <int LOGP, int NPRO>
__device__ __forceinline__ void gather_one(int g, int lane, const int* __restrict__ begs,
                                           const int* __restrict__ ends,
                                           const int* __restrict__ ssrc,
                                           const unsigned* __restrict__ feat,
                                           unsigned* __restrict__ mean) {
    const int P = 1 << LOGP;
    const h2 SLO = h2{(_Float16)1.0f, (_Float16)0.0f};
    const h2 SHI = h2{(_Float16)0.0f, (_Float16)1.0f};
    int beg = begs[g], end = ends[g];
    int n = end - beg;
    float alo = 0.0f, ahi = 0.0f;
    if (n > 0) {
        const int nm1 = n - 1;
        int s[NPRO];
#pragma unroll
        for (int j = 0; j < NPRO; j++) s[j] = ssrc[beg + min(j, nm1)];
        unsigned v[NPRO];
#pragma unroll
        for (int j = 0; j < NPRO; j++) v[j] = feat[(size_t)(unsigned)s[j] * P + lane];
#pragma unroll
        for (int j = 0; j < NPRO; j++) {
            U32H2 u; u.u = (j < n) ? v[j] : 0u;
            alo = dot2sel(alo, u.h, SLO); ahi = dot2sel(ahi, u.h, SHI);
        }
        int i = beg + NPRO;
        for (; i + 8 <= end; i += 8) {
            int t0 = ssrc[i],     t1 = ssrc[i + 1], t2 = ssrc[i + 2], t3 = ssrc[i + 3];
            int t4 = ssrc[i + 4], t5 = ssrc[i + 5], t6 = ssrc[i + 6], t7 = ssrc[i + 7];
            unsigned w0 = feat[(size_t)t0 * P + lane];
            unsigned w1 = feat[(size_t)t1 * P + lane];
            unsigned w2 = feat[(size_t)t2 * P + lane];
            unsigned w3 = feat[(size_t)t3 * P + lane];
            unsigned w4 = feat[(size_t)t4 * P + lane];
            unsigned w5 = feat[(size_t)t5 * P + lane];
            unsigned w6 = feat[(size_t)t6 * P + lane];
            unsigned w7 = feat[(size_t)t7 * P + lane];
            U32H2 u;
            u.u = w0; alo = dot2sel(alo, u.h, SLO); ahi = dot2sel(ahi, u.h, SHI);
            u.u = w1; alo = dot2sel(alo, u.h, SLO); ahi = dot2sel(ahi, u.h, SHI);
            u.u = w2; alo = dot2sel(alo, u.h, SLO); ahi = dot2sel(ahi, u.h, SHI);
            u.u = w3; alo = dot2sel(alo, u.h, SLO); ahi = dot2sel(ahi, u.h, SHI);
            u.u = w4; alo = dot2sel(alo, u.h, SLO); ahi = dot2sel(ahi, u.h, SHI);
            u.u = w5; alo = dot2sel(alo, u.h, SLO); ahi = dot2sel(ahi, u.h, SHI);
            u.u = w6; alo = dot2sel(alo, u.h, SLO); ahi = dot2sel(ahi, u.h, SHI);
            u.u = w7; alo = dot2sel(alo, u.h, SLO); ahi = dot2sel(ahi, u.h, SHI);
        }
        for (; i < end; i++) {
            U32H2 u; u.u = feat[(size_t)ssrc[i] * P + lane];
            alo = dot2sel(alo, u.h, SLO); ahi = dot2sel(ahi, u.h, SHI);
        }
    }
    float ic = (n > 0) ? 1.0f / (float)n : 0.0f;
    mean[(size_t)g * P + lane] = pk2(alo * ic, ahi * ic);
}

#define G1 (N_TP * 32)
#define G2 (G1 + N_FM * 32)
#define G3 (G2 + N_FM * 16)
#define G4 (G3 + N_SM * 16)
#define G5 (G4 + N_FM * 16)

__global__ void __launch_bounds__(256)
gather_all(const int* __restrict__ el_beg, const int* __restrict__ el_end,
           const int* __restrict__ so_all,
           const unsigned* __restrict__ x_fm_f, const unsigned* __restrict__ pe_f,
           unsigned* __restrict__ mean_qoq, unsigned* __restrict__ mean_cp,
           unsigned* __restrict__ mean_rb, unsigned* __restrict__ mean_bp,
           unsigned* __restrict__ mean_cd) {
    int gid = blockIdx.x * blockDim.x + threadIdx.x;
    if (gid < G1) {
        gather_one<5, 16>(gid >> 5, gid & 31, el_beg + EL_BP, el_end + EL_BP, so_all, x_fm_f, mean_bp);
    } else if (gid < G2) {
        int i = gid - G1;
        gather_one<5, 16>(i >> 5, i & 31, el_beg + EL_QOQ, el_end + EL_QOQ, so_all, x_fm_f, mean_qoq);
    } else if (gid < G3) {
        int i = gid - G2;
        gather_one<4, 8>(i >> 4, i & 15, el_beg + EL_CP, el_end + EL_CP, so_all, pe_f, mean_cp);
    } else if (gid < G4) {
        int i = gid - G3;
        gather_one<4, 8>(i >> 4, i & 15, el_beg + EL_CD, el_end + EL_CD, so_all, pe_f, mean_cd);
    } else if (gid < G5) {
        int i = gid - G4;
        gather_one<4, 16>(i >> 4, i & 15, el_beg + EL_RB, el_end + EL_RB, so_all, pe_f, mean_rb);
    }
}

// ---------------------------------------------------------------- MFMA row kernels
// A-frag (16x32 f16): lane holds row=(lane&15), k=(lane>>4)*8..+7 -> contiguous uint4 at
//   u32 off = ks*16 + (lane>>4)*4 within the row. B-frag staged in LDS frag-major.
// C-frag: col=lane&15, row=(lane>>4)*4+reg  [verified layout, learn_hip m89]
// Column sums: block-level LDS reduce -> one 128-float partial per block (NO atomics).

__global__ void __launch_bounds__(256)
fm_mfma(const unsigned* __restrict__ mq, const unsigned* __restrict__ mc,
        const unsigned* __restrict__ mr, const unsigned* __restrict__ xf,
        const unsigned* __restrict__ wfrag, const float* __restrict__ bias,
        const float* __restrict__ ln_g, const float* __restrict__ ln_b,
        float* __restrict__ part) {
    __shared__ uint4 wlds[48 * 64];  // 48 KB
    const int tid = threadIdx.x, lane = tid & 63, wid = tid >> 6;
    for (int i = tid; i < 48 * 64; i += 256) wlds[i] = ((const uint4*)wfrag)[i];
    const int c0 = lane & 15, ko = lane >> 4;
    float bias_[8], g_[8], b_[8], colacc[8];
#pragma unroll
    for (int nt = 0; nt < 8; nt++) {
        int c = nt * 16 + c0;
        bias_[nt] = bias[c]; g_[nt] = ln_g[c]; b_[nt] = ln_b[c]; colacc[nt] = 0.0f;
    }
    __syncthreads();
    const f32x4_t zero = {0.0f, 0.0f, 0.0f, 0.0f};
    const int ntiles = N_FM / 16;
    for (int tile = blockIdx.x * 4 + wid; tile < ntiles; tile += gridDim.x * 4) {
        const size_t row = (size_t)tile * 16 + c0;
        uint4 av[6];
        av[0] = ((const uint4*)mq)[row * 8 + ko];
        av[1] = ((const uint4*)mq)[row * 8 + 4 + ko];
        av[2] = ((const uint4*)mc)[row * 4 + ko];
        av[3] = ((const uint4*)mr)[row * 4 + ko];
        av[4] = ((const uint4*)xf)[row * 8 + ko];
        av[5] = ((const uint4*)xf)[row * 8 + 4 + ko];
        f32x4_t acc[8];
#pragma unroll
        for (int nt = 0; nt < 8; nt++) acc[nt] = zero;
#pragma unroll
        for (int ks = 0; ks < 6; ks++) {
            f16x8_t af = as_h8(av[ks]);
#pragma unroll
            for (int nt = 0; nt < 8; nt++)
                acc[nt] = __builtin_amdgcn_mfma_f32_16x16x32_f16(
                    af, as_h8(wlds[(ks * 8 + nt) * 64 + lane]), acc[nt], 0, 0, 0);
        }
#pragma unroll
        for (int r = 0; r < 4; r++) {
            float yv[8]; float s = 0.0f, q = 0.0f;
#pragma unroll
            for (int nt = 0; nt < 8; nt++) {
                float y = (acc[nt][r] + bias_[nt]) * (1.0f / 3.0f);
                yv[nt] = y; s += y; q += y * y;
            }
#pragma unroll
            for (int off = 1; off < 16; off <<= 1) { s += __shfl_xor(s, off); q += __shfl_xor(q, off); }
            float mu = s * (1.0f / 128.0f);
            float var = fmaxf(q * (1.0f / 128.0f) - mu * mu, 0.0f);
            float rs = rsqrtf(var + 1e-5f);
#pragma unroll
            for (int nt = 0; nt < 8; nt++)
                colacc[nt] += fmaxf((yv[nt] - mu) * rs * g_[nt] + b_[nt], 0.0f);
        }
    }
#pragma unroll
    for (int nt = 0; nt < 8; nt++) {
        colacc[nt] += __shfl_xor(colacc[nt], 16);
        colacc[nt] += __shfl_xor(colacc[nt], 32);
    }
    __syncthreads();  // all waves done with wlds; reuse as reduction scratch
    float* sred = (float*)wlds;
    if (lane < 16) {
#pragma unroll
        for (int nt = 0; nt < 8; nt++) sred[wid * 128 + nt * 16 + lane] = colacc[nt];
    }
    __syncthreads();
    if (tid < 128)
        part[(size_t)blockIdx.x * 128 + tid] =
            sred[tid] + sred[128 + tid] + sred[256 + tid] + sred[384 + tid];
}

template <int KSA, int KSB>
__global__ void __launch_bounds__(256)
rows_mfma(int ntiles, const unsigned* __restrict__ mA, const unsigned* __restrict__ xB,
          const unsigned* __restrict__ wfrag, const float* __restrict__ bl,
          const float* __restrict__ ln_g, const float* __restrict__ ln_b,
          float* __restrict__ part) {
    constexpr int KS = KSA + KSB;
    __shared__ uint4 wlds[KS * 8 * 64];
    const int tid = threadIdx.x, lane = tid & 63, wid = tid >> 6;
    for (int i = tid; i < KS * 8 * 64; i += 256) wlds[i] = ((const uint4*)wfrag)[i];
    const int c0 = lane & 15, ko = lane >> 4;
    float bias_[8], g_[8], b_[8], colacc[8];
#pragma unroll
    for (int nt = 0; nt < 8; nt++) {
        int c = nt * 16 + c0;
        bias_[nt] = bl[c]; g_[nt] = ln_g[c]; b_[nt] = ln_b[c]; colacc[nt] = 0.0f;
    }
    __syncthreads();
    const f32x4_t zero = {0.0f, 0.0f, 0.0f, 0.0f};
    for (int tile = blockIdx.x * 4 + wid; tile < ntiles; tile += gridDim.x * 4) {
        const size_t row = (size_t)tile * 16 + c0;
        uint4 av[KS];
#pragma unroll
        for (int ks = 0; ks < KSA; ks++) av[ks] = ((const uint4*)mA)[row * (KSA * 4) + ks * 4 + ko];
#pragma unroll
        for (int ks = 0; ks < KSB; ks++) av[KSA + ks] = ((const uint4*)xB)[row * (KSB * 4) + ks * 4 + ko];
        f32x4_t acc[8];
#pragma unroll
        for (int nt = 0; nt < 8; nt++) acc[nt] = zero;
#pragma unroll
        for (int ks = 0; ks < KS; ks++) {
            f16x8_t af = as_h8(av[ks]);
#pragma unroll
            for (int nt = 0; nt < 8; nt++)
                acc[nt] = __builtin_amdgcn_mfma_f32_16x16x32_f16(
                    af, as_h8(wlds[(ks * 8 + nt) * 64 + lane]), acc[nt], 0, 0, 0);
        }
#pragma unroll
        for (int r = 0; r < 4; r++) {
            float yv[8]; float s = 0.0f, q = 0.0f;
#pragma unroll
            for (int nt = 0; nt < 8; nt++) {
                float y = acc[nt][r] + bias_[nt];
                yv[nt] = y; s += y; q += y * y;
            }
#pragma unroll
            for (int off = 1; off < 16; off <<= 1) { s += __shfl_xor(s, off); q += __shfl_xor(q, off); }
            float mu = s * (1.0f / 128.0f);
            float var = fmaxf(q * (1.0f / 128.0f) - mu * mu, 0.0f);
            float rs = rsqrtf(var + 1e-5f);
#pragma unroll
            for (int nt = 0; nt < 8; nt++)
                colacc[nt] += fmaxf((yv[nt] - mu) * rs * g_[nt] + b_[nt], 0.0f);
        }
    }
#pragma unroll
    for (int nt = 0; nt < 8; nt++) {
        colacc[nt] += __shfl_xor(colacc[nt], 16);
        colacc[nt] += __shfl_xor(colacc[nt], 32);
    }
    __syncthreads();  // all waves done with wlds; reuse as reduction scratch
    float* sred = (float*)wlds;
    if (lane < 16) {
#pragma unroll
        for (int nt = 0; nt < 8; nt++) sred[wid * 128 + nt * 16 + lane] = colacc[nt];
    }
    __syncthreads();
    if (tid < 128)
        part[(size_t)blockIdx.x * 128 + tid] =
            sred[tid] + sred[128 + tid] + sred[256 + tid] + sred[384 + tid];
}

// ---------------------------------------------------------------- partial-sum reduction (replaces atomics)
__global__ void __launch_bounds__(512)
reduce_cols(const float* __restrict__ part, float* __restrict__ colsum) {
    __shared__ float lds[512];
    const int t = threadIdx.x, col = t & 127, sl = t >> 7;
    int cnt, srcoff, dst;
    if (blockIdx.x == 0)      { cnt = GRID_FM; srcoff = 0;                         dst = 0;   }
    else if (blockIdx.x == 1) { cnt = GRID_TP; srcoff = GRID_FM * 128;             dst = 128; }
    else                      { cnt = GRID_SM; srcoff = (GRID_FM + GRID_TP) * 128; dst = 256; }
    float a = 0.0f;
    for (int i = sl; i < cnt; i += 4) a += part[srcoff + i * 128 + col];
    lds[t] = a;
    __syncthreads();
    if (t < 128) colsum[dst + t] = lds[t] + lds[128 + t] + lds[256 + t] + lds[384 + t];
}

// ---------------------------------------------------------------- head MLP -> scalar (split-K)
__global__ void head_kernel(const float* __restrict__ colsum, const float* __restrict__ gf,
                            const float* __restrict__ W1, const float* __restrict__ b1,
                            const float* __restrict__ W2, const float* __restrict__ b2,
                            float* __restrict__ out) {
    __shared__ float h[448];
    __shared__ float sh[512];
    __shared__ float h1[64];
    int t = threadIdx.x;  // 512 threads
    if (t < 128) h[t] = colsum[t] * (1.0f / N_FM);
    else if (t < 256) h[t] = colsum[t] * (1.0f / N_TP);
    else if (t < 384) h[t] = colsum[t] * (1.0f / N_SM);
    else if (t < 448) h[t] = gf[t - 384];
    __syncthreads();
    {
        int col = t & 63, slice = t >> 6;
        float a = 0.0f;
        for (int k = slice * 56; k < slice * 56 + 56; k++) a += h[k] * W1[k * 64 + col];
        sh[slice * 64 + col] = a;
    }
    __syncthreads();
    if (t < 64) {
        float a = b1[t];
#pragma unroll
        for (int s = 0; s < 8; s++) a += sh[s * 64 + t];
        h1[t] = fmaxf(a, 0.0f);
    }
    __syncthreads();
    if (t < 64) {
        float p = h1[t] * W2[t];
#pragma unroll
        for (int off = 1; off < 64; off <<= 1) p += __shfl_xor(p, off);
        if (t == 0) out[0] = p + b2[0];
    }
}

extern "C" void kernel_launch(void* const* d_in, const int* in_sizes, int n_in,
                              void* d_out, int out_size, void* d_ws, size_t ws_size,
                              hipStream_t stream) {
    const float* x_fm = (const float*)d_in[0];
    const float* x_sm = (const float*)d_in[1];
    const float* period_vol = (const float*)d_in[2];
    const float* gf = (const float*)d_in[3];
    const float* pe_table = (const float*)d_in[4];
    const int* qoq_src = (const int*)d_in[5];
    const int* qoq_dst = (const int*)d_in[6];
    const int* bp_src = (const int*)d_in[7];
    const int* bp_dst = (const int*)d_in[8];
    const int* cp_src = (const int*)d_in[9];
    const int* cp_dst = (const int*)d_in[10];
    const int* cd_src = (const int*)d_in[11];
    const int* cd_dst = (const int*)d_in[12];
    const int* rb_src = (const int*)d_in[13];
    const int* rb_dst = (const int*)d_in[14];
    const float* qoq_Wl = (const float*)d_in[15];
    const float* qoq_bl = (const float*)d_in[16];
    const float* qoq_Wr = (const float*)d_in[17];
    const float* bp_Wl = (const float*)d_in[18];
    const float* bp_bl = (const float*)d_in[19];
    const float* bp_Wr = (const float*)d_in[20];
    const float* cp_Wl = (const float*)d_in[21];
    const float* cp_bl = (const float*)d_in[22];
    const float* cp_Wr = (const float*)d_in[23];
    const float* cd_Wl = (const float*)d_in[24];
    const float* cd_bl = (const float*)d_in[25];
    const float* cd_Wr = (const float*)d_in[26];
    const float* rb_Wl = (const float*)d_in[27];
    const float* rb_bl = (const float*)d_in[28];
    const float* rb_Wr = (const float*)d_in[29];
    const float* ln_fm_g = (const float*)d_in[30];
    const float* ln_fm_b = (const float*)d_in[31];
    const float* ln_tp_g = (const float*)d_in[32];
    const float* ln_tp_b = (const float*)d_in[33];
    const float* ln_sm_g = (const float*)d_in[34];
    const float* ln_sm_b = (const float*)d_in[35];
    const float* head_W1 = (const float*)d_in[36];
    const float* head_b1 = (const float*)d_in[37];
    const float* head_W2 = (const float*)d_in[38];
    const float* head_b2 = (const float*)d_in[39];

    // workspace (4-byte words); zero region: bucket cursors + colsum
    unsigned* wsu = (unsigned*)d_ws;
    size_t off = 0;
    int* bwork = (int*)(wsu + off); off += NBUCK;
    float* colsum = (float*)(wsu + off); off += 384;
    size_t zero_words = off;
    off = (off + 3) & ~(size_t)3;  // 16B-align everything downstream (uint4 loads)
    unsigned* pairs = wsu + off; off += PAIRS_CAP;
    int* so_all = (int*)(wsu + off); off += PAIRS_CAP;
    int* el_beg = (int*)(wsu + off); off += NTOT;
    int* el_end = (int*)(wsu + off); off += NTOT;
    unsigned* mean_qoq = wsu + off; off += (size_t)N_FM * 32;
    unsigned* mean_cp  = wsu + off; off += (size_t)N_FM * 16;
    unsigned* mean_rb  = wsu + off; off += (size_t)N_FM * 16;
    unsigned* mean_bp  = wsu + off; off += (size_t)N_TP * 32;
    unsigned* mean_cd  = wsu + off; off += (size_t)N_SM * 16;
    unsigned* pe_f     = wsu + off; off += (size_t)N_TP * 16;
    unsigned* x_fm_f   = wsu + off; off += (size_t)N_FM * 32;
    unsigned* x_sm_f   = wsu + off; off += (size_t)N_SM * 16;
    unsigned* wf_fm    = wsu + off; off += 12288;
    unsigned* wf_tp    = wsu + off; off += 6144;
    unsigned* wf_sm    = wsu + off; off += 4096;
    float* bias_fm     = (float*)(wsu + off); off += 128;

    // per-block column partials alias the (dead-after-esort) pairs buffer
    float* part_fm = (float*)pairs;                 // GRID_FM*128
    float* part_tp = part_fm + GRID_FM * 128;       // GRID_TP*128
    float* part_sm = part_tp + GRID_TP * 128;       // GRID_SM*128

    hipMemsetAsync(d_ws, 0, zero_words * 4, stream);

    EdgePtrs EP{qoq_src, qoq_dst, cp_src, cp_dst, rb_src, rb_dst, bp_src, bp_dst, cd_src, cd_dst};
    PackPtrs PK{x_fm, x_sm, pe_table, period_vol,
                qoq_Wl, cp_Wl, rb_Wl, qoq_Wr, cp_Wr, rb_Wr,
                bp_Wl, bp_Wr, cd_Wl, cd_Wr,
                qoq_bl, cp_bl, rb_bl,
                x_fm_f, x_sm_f, pe_f, wf_fm, wf_tp, wf_sm, bias_fm};

    // fused bin + pack (independent work overlapped in one dispatch)
    bin_pack<<<NCHUNK + PACK_BLOCKS, 256, 0, stream>>>(EP, PK, bwork, pairs);
    esort<<<NBUCK, 256, 0, stream>>>(bwork, pairs, so_all, el_beg, el_end);
    gather_all<<<(G5 + 255) / 256, 256, 0, stream>>>(el_beg, el_end, so_all, x_fm_f, pe_f,
                                                     mean_qoq, mean_cp, mean_rb, mean_bp, mean_cd);

    // MFMA row kernels (fused GEMM + LN + ReLU + per-block column partials)
    fm_mfma<<<GRID_FM, 256, 0, stream>>>(mean_qoq, mean_cp, mean_rb, x_fm_f, wf_fm,
                                         bias_fm, ln_fm_g, ln_fm_b, part_fm);
    rows_mfma<2, 1><<<GRID_TP, 256, 0, stream>>>(N_TP / 16, mean_bp, pe_f, wf_tp,
                                                 bp_bl, ln_tp_g, ln_tp_b, part_tp);
    rows_mfma<1, 1><<<GRID_SM, 256, 0, stream>>>(N_SM / 16, mean_cd, x_sm_f, wf_sm,
                                                 cd_bl, ln_sm_g, ln_sm_b, part_sm);

    reduce_cols<<<3, 512, 0, stream>>>(part_fm, colsum);

    head_kernel<<<1, 512, 0, stream>>>(colsum, gf, head_W1, head_b1, head_W2, head_b2,
                                       (float*)d_out);
}

// Round 13
// 436.634 us; speedup vs baseline: 1.0218x; 1.0213x over previous
//
#include <hip/hip_runtime.h>
#include <hip/hip_fp16.h>

#define N_FM 100000
#define N_TP 4096
#define N_SM 100000
#define HID 128
#define E_QOQ 1000000
#define E_BP 1000000
#define E_CP 500000
#define E_CD 500000
#define E_RB 1000000
#define E_TOT 4000000

// global edge-id order: qoq | cp | rb | bp | cd
#define EO_CP  1000000
#define EO_RB  1500000
#define EO_BP  2500000
#define EO_CD  3500000

// element space (concatenated): qoq | cp | rb | bp | cd
#define EL_QOQ 0
#define EL_CP  (N_FM)
#define EL_RB  (2 * N_FM)
#define EL_BP  (3 * N_FM)
#define EL_CD  (3 * N_FM + N_TP)
#define NTOT   (3 * N_FM + N_TP + N_SM)

// buckets: qoq 128 elems (shift 7) | cp/rb/cd 256 (shift 8) | bp 32 (shift 5)
#define BB_QOQ 0
#define BB_CP  782
#define BB_RB  1173
#define BB_BP  1564
#define BB_CD  1692
#define NBUCK  2083
// CHUNK=8192: middle of the measured bin tradeoff curve. 4096 -> ~2 edges per
// block-slice -> ~14x pairs write amp (262MB, r12 PMC); 16384 -> 2.2x amp but
// latency-starved (245 blocks, 107us, r2). 8192 = 489 blocks, slices ~4 edges.
#define CHUNK  8192
#define NCHUNK ((E_TOT + CHUNK - 1) / CHUNK)
#define EPB    (CHUNK / 256)

#define PAIRS_CAP 5784064

// row-kernel grids (must match partial-buffer layout)
#define GRID_FM 768
#define GRID_TP 64
#define GRID_SM 1024

__device__ __forceinline__ int bucket_base(int b) {
    if (b < BB_CP) return b * 2048;
    if (b < BB_RB) return 1601536 + (b - BB_CP) * 2048;
    if (b < BB_BP) return 2402304 + (b - BB_RB) * 3584;
    if (b < BB_CD) return 3803648 + (b - BB_BP) * 9216;
    return 4983296 + (b - BB_CD) * 2048;
}

typedef _Float16 h2 __attribute__((ext_vector_type(2)));
typedef _Float16 f16x8_t __attribute__((ext_vector_type(8)));
typedef float f32x4_t __attribute__((ext_vector_type(4)));

union U32H2 { unsigned u; h2 h; };
union U4H8 { uint4 u; f16x8_t h; };

#if defined(__has_builtin)
#if __has_builtin(__builtin_amdgcn_fdot2)
#define HAVE_FDOT2 1
#endif
#endif

__device__ __forceinline__ unsigned pk2(float a, float b) {
    U32H2 x; x.h = h2{(_Float16)a, (_Float16)b}; return x.u;
}
__device__ __forceinline__ f16x8_t as_h8(uint4 v) { U4H8 x; x.u = v; return x.h; }

// acc += v . sel  (one v_dot2_f32_f16 instead of 2x cvt + 2x add)
__device__ __forceinline__ float dot2sel(float acc, h2 v, h2 sel) {
#ifdef HAVE_FDOT2
    return __builtin_amdgcn_fdot2(v, sel, acc, false);
#else
    return acc + (float)v[0] * (float)sel[0] + (float)v[1] * (float)sel[1];
#endif
}

// ---------------------------------------------------------------- unified pack kernel
// feature sections vectorized float4 (16B/lane)
#define R1 (N_FM * 16)
#define R2 (R1 + N_SM * 8)
#define R3 (R2 + N_TP * 8)
// MFMA-frag-major weights: element j -> f=j>>8 (frag = ks*8+nt), lane=(j>>2)&63, jj=j&3
//   p (h2 pair row) = (f>>3)*16 + ((lane>>4)<<2) + jj ; c = (f&7)*16 + (lane&15)
#define R4 (R3 + 12288)   // fm: 6 ks * 8 nt * 256
#define R5 (R4 + 6144)    // tp: 3 ks * 8 nt * 256
#define R6 (R5 + 4096)    // sm: 2 ks * 8 nt * 256
#define R7 (R6 + 128)     // combined fm bias

__device__ __forceinline__ unsigned pack_pair(const float* W, int p, int c) {
    return pk2(W[(2 * p) * HID + c], W[(2 * p + 1) * HID + c]);
}

__global__ void pack_all(const float* __restrict__ x_fm, const float* __restrict__ x_sm,
                         const float* __restrict__ pe_table, const float* __restrict__ pvol,
                         const float* __restrict__ qoq_Wl, const float* __restrict__ cp_Wl,
                         const float* __restrict__ rb_Wl, const float* __restrict__ qoq_Wr,
                         const float* __restrict__ cp_Wr, const float* __restrict__ rb_Wr,
                         const float* __restrict__ bp_Wl, const float* __restrict__ bp_Wr,
                         const float* __restrict__ cd_Wl, const float* __restrict__ cd_Wr,
                         const float* __restrict__ qoq_bl, const float* __restrict__ cp_bl,
                         const float* __restrict__ rb_bl,
                         unsigned* __restrict__ x_fm_f, unsigned* __restrict__ x_sm_f,
                         unsigned* __restrict__ pe_f, unsigned* __restrict__ wf_fm,
                         unsigned* __restrict__ wf_tp, unsigned* __restrict__ wf_sm,
                         float* __restrict__ bias_fm) {
    int gid = blockIdx.x * blockDim.x + threadIdx.x;
    if (gid < R1) {
        float4 t = ((const float4*)x_fm)[gid];
        uint2 o; o.x = pk2(t.x, t.y); o.y = pk2(t.z, t.w);
        ((uint2*)x_fm_f)[gid] = o;
    } else if (gid < R2) {
        int i = gid - R1;
        float4 t = ((const float4*)x_sm)[i];
        uint2 o; o.x = pk2(t.x, t.y); o.y = pk2(t.z, t.w);
        ((uint2*)x_sm_f)[i] = o;
    } else if (gid < R3) {
        int i = gid - R2;
        float4 t = ((const float4*)pe_table)[i];
        float v = pvol[i >> 3];
        uint2 o; o.x = pk2(t.x * v, t.y * v); o.y = pk2(t.z * v, t.w * v);
        ((uint2*)pe_f)[i] = o;
    } else if (gid < R4) {
        int j = gid - R3;
        int f = j >> 8, lr = (j >> 2) & 63, jj = j & 3;
        int p = (f >> 3) * 16 + ((lr >> 4) << 2) + jj;
        int c = (f & 7) * 16 + (lr & 15);
        unsigned v;
        if (p < 32) v = pack_pair(qoq_Wl, p, c);
        else if (p < 48) v = pack_pair(cp_Wl, p - 32, c);
        else if (p < 64) v = pack_pair(rb_Wl, p - 48, c);
        else {
            int pp = p - 64;
            float u0 = qoq_Wr[(2 * pp) * HID + c] + cp_Wr[(2 * pp) * HID + c] + rb_Wr[(2 * pp) * HID + c];
            float u1 = qoq_Wr[(2 * pp + 1) * HID + c] + cp_Wr[(2 * pp + 1) * HID + c] + rb_Wr[(2 * pp + 1) * HID + c];
            v = pk2(u0, u1);
        }
        wf_fm[j] = v;
    } else if (gid < R5) {
        int j = gid - R4;
        int f = j >> 8, lr = (j >> 2) & 63, jj = j & 3;
        int p = (f >> 3) * 16 + ((lr >> 4) << 2) + jj;
        int c = (f & 7) * 16 + (lr & 15);
        wf_tp[j] = (p < 32) ? pack_pair(bp_Wl, p, c) : pack_pair(bp_Wr, p - 32, c);
    } else if (gid < R6) {
        int j = gid - R5;
        int f = j >> 8, lr = (j >> 2) & 63, jj = j & 3;
        int p = (f >> 3) * 16 + ((lr >> 4) << 2) + jj;
        int c = (f & 7) * 16 + (lr & 15);
        wf_sm[j] = (p < 16) ? pack_pair(cd_Wl, p, c) : pack_pair(cd_Wr, p - 16, c);
    } else if (gid < R7) {
        int c = gid - R6;
        bias_fm[c] = qoq_bl[c] + cp_bl[c] + rb_bl[c];
    }
}

// ---------------------------------------------------------------- edge decode (branchless: selects, then ONE load)
struct EdgePtrs {
    const int *qs, *qd, *cs, *cd_, *rs, *rd, *bs, *bd, *ds, *dd;
};

template <bool NEED_SRC>
__device__ __forceinline__ void edge_decode(const EdgePtrs& P, int e, int& bucket, int& dl, int& src) {
    const int* dp = P.qd; const int* sp = P.qs;
    int i = e, bb = BB_QOQ, sh = 7;
    if (e >= EO_CP) { i = e - EO_CP; dp = P.cd_; sp = P.cs; bb = BB_CP; sh = 8; }
    if (e >= EO_RB) { i = e - EO_RB; dp = P.rd;  sp = P.rs; bb = BB_RB; sh = 8; }
    if (e >= EO_BP) { i = e - EO_BP; dp = P.bd;  sp = P.bs; bb = BB_BP; sh = 5; }
    if (e >= EO_CD) { i = e - EO_CD; dp = P.dd;  sp = P.ds; bb = BB_CD; sh = 8; }
    int d = dp[i];
    bucket = bb + (d >> sh);
    dl = d & ((1 << sh) - 1);
    if (NEED_SRC) src = sp[i];
}

// ---------------------------------------------------------------- bin: block-reserved bucket scatter
// Single decode pass: (bucket|dl, src) cached across both phases.
// Block-reserved bucket slices keep pairs writes per-block contiguous; slice
// size (CHUNK/NBUCK) controls the write-RMW amplification (r12 PMC: 14x @4096).
__global__ void __launch_bounds__(256) bin_kernel(EdgePtrs P, int* __restrict__ bwork,
                                                  unsigned* __restrict__ pairs) {
    __shared__ int lh[NBUCK];
    const int tid = threadIdx.x;
    for (int i = tid; i < NBUCK; i += 256) lh[i] = 0;
    __syncthreads();
    const int base = blockIdx.x * CHUNK;
    const int lim = min(base + CHUNK, E_TOT);
    unsigned ebd[EPB]; int esr[EPB];
#pragma unroll
    for (int j = 0; j < EPB; j++) {
        int e = base + tid + j * 256;
        if (e < lim) {
            int b, dl, s;
            edge_decode<true>(P, e, b, dl, s);
            ebd[j] = ((unsigned)b << 8) | (unsigned)dl;   // b < 4096, dl < 256
            esr[j] = s;
            atomicAdd(&lh[b], 1);
        }
    }
    __syncthreads();
#pragma unroll
    for (int u = 0; u < (NBUCK + 255) / 256; u++) {
        int b = tid + u * 256;
        if (b < NBUCK) {
            int c = lh[b];
            lh[b] = c ? bucket_base(b) + atomicAdd(&bwork[b], c) : 0;
        }
    }
    __syncthreads();
#pragma unroll
    for (int j = 0; j < EPB; j++) {
        int e = base + tid + j * 256;
        if (e < lim) {
            int b = (int)(ebd[j] >> 8);
            int pos = atomicAdd(&lh[b], 1);
            pairs[pos] = ((ebd[j] & 255u) << 24) | (unsigned)esr[j];
        }
    }
}

// ---------------------------------------------------------------- esort: per-bucket LDS counting sort by element
// Wave-shuffle scan (6 shfl steps + 2 barriers).
__global__ void __launch_bounds__(256) esort(const int* __restrict__ bwork,
                                             const unsigned* __restrict__ pairs,
                                             int* __restrict__ so,
                                             int* __restrict__ el_beg, int* __restrict__ el_end) {
    __shared__ int hist[256];
    __shared__ int wsum[4];
    __shared__ int so_lds[9216];  // max bucket capacity (bp)
    const int b = blockIdx.x;
    const int tid = threadIdx.x;
    const int lane = tid & 63, wv = tid >> 6;
    int beg = bucket_base(b);
    int end = beg + bwork[b];
    int egbase, ne;
    if (b < BB_CP)      { int e0 = (b - BB_QOQ) << 7; egbase = EL_QOQ + e0; ne = min(128, N_FM - e0); }
    else if (b < BB_RB) { int e0 = (b - BB_CP) << 8;  egbase = EL_CP + e0;  ne = min(256, N_FM - e0); }
    else if (b < BB_BP) { int e0 = (b - BB_RB) << 8;  egbase = EL_RB + e0;  ne = min(256, N_FM - e0); }
    else if (b < BB_CD) { int e0 = (b - BB_BP) << 5;  egbase = EL_BP + e0;  ne = min(32, N_TP - e0); }
    else                { int e0 = (b - BB_CD) << 8;  egbase = EL_CD + e0;  ne = min(256, N_SM - e0); }
    hist[tid] = 0;
    __syncthreads();
    for (int e = beg + tid; e < end; e += 256)
        atomicAdd(&hist[pairs[e] >> 24], 1);
    __syncthreads();
    int v = hist[tid];
    // inclusive wave scan
    int x = v;
#pragma unroll
    for (int off = 1; off < 64; off <<= 1) {
        int u = __shfl_up(x, off);
        if (lane >= off) x += u;
    }
    if (lane == 63) wsum[wv] = x;
    __syncthreads();
    int wbase = 0;
#pragma unroll
    for (int w = 0; w < 4; w++) wbase += (w < wv) ? wsum[w] : 0;
    int excl = wbase + x - v;
    if (tid < ne) {
        el_beg[egbase + tid] = beg + excl;
        el_end[egbase + tid] = beg + excl + v;
    }
    hist[tid] = excl;  // bucket-relative cursor
    __syncthreads();
    for (int e = beg + tid; e < end; e += 256) {
        unsigned pr = pairs[e];
        int dl = pr >> 24;
        int pos = atomicAdd(&hist[dl], 1);
        so_lds[pos] = (int)(pr & 0xFFFFFF);
    }
    __syncthreads();
    const int n = end - beg;
    for (int i = tid; i < n; i += 256) so[beg + i] = so_lds[i];
}

// ---------------------------------------------------------------- gather: element CSR, register fp32 accumulate
// Masked NPRO-slot prologue: ONE index stage + ONE fully-parallel feature stage
// covers deg<=NPRO (avg deg 10 / 5); overflow uses 8-deep continuation.
template <int LOGP, int NPRO>
__device__ __forceinline__ void gather_one(int g, int lane, const int* __restrict__ begs,
                                           const int* __restrict__ ends,
                                           const int* __restrict__ ssrc,
                                           const unsigned* __restrict__ feat,
                                           unsigned* __restrict__ mean) {
    const int P = 1 << LOGP;
    const h2 SLO = h2{(_Float16)1.0f, (_Float16)0.0f};
    const h2 SHI = h2{(_Float16)0.0f, (_Float16)1.0f};
    int beg = begs[g], end = ends[g];
    int n = end - beg;
    float alo = 0.0f, ahi = 0.0f;
    if (n > 0) {
        const int nm1 = n - 1;
        int s[NPRO];
#pragma unroll
        for (int j = 0; j < NPRO; j++) s[j] = ssrc[beg + min(j, nm1)];
        unsigned v[NPRO];
#pragma unroll
        for (int j = 0; j < NPRO; j++) v[j] = feat[(size_t)(unsigned)s[j] * P + lane];
#pragma unroll
        for (int j = 0; j < NPRO; j++) {
            U32H2 u; u.u = (j < n) ? v[j] : 0u;
            alo = dot2sel(alo, u.h, SLO); ahi = dot2sel(ahi, u.h, SHI);
        }
        int i = beg + NPRO;
        for (; i + 8 <= end; i += 8) {
            int t0 = ssrc[i],     t1 = ssrc[i + 1], t2 = ssrc[i + 2], t3 = ssrc[i + 3];
            int t4 = ssrc[i + 4], t5 = ssrc[i + 5], t6 = ssrc[i + 6], t7 = ssrc[i + 7];
            unsigned w0 = feat[(size_t)t0 * P + lane];
            unsigned w1 = feat[(size_t)t1 * P + lane];
            unsigned w2 = feat[(size_t)t2 * P + lane];
            unsigned w3 = feat[(size_t)t3 * P + lane];
            unsigned w4 = feat[(size_t)t4 * P + lane];
            unsigned w5 = feat[(size_t)t5 * P + lane];
            unsigned w6 = feat[(size_t)t6 * P + lane];
            unsigned w7 = feat[(size_t)t7 * P + lane];
            U32H2 u;
            u.u = w0; alo = dot2sel(alo, u.h, SLO); ahi = dot2sel(ahi, u.h, SHI);
            u.u = w1; alo = dot2sel(alo, u.h, SLO); ahi = dot2sel(ahi, u.h, SHI);
            u.u = w2; alo = dot2sel(alo, u.h, SLO); ahi = dot2sel(ahi, u.h, SHI);
            u.u = w3; alo = dot2sel(alo, u.h, SLO); ahi = dot2sel(ahi, u.h, SHI);
            u.u = w4; alo = dot2sel(alo, u.h, SLO); ahi = dot2sel(ahi, u.h, SHI);
            u.u = w5; alo = dot2sel(alo, u.h, SLO); ahi = dot2sel(ahi, u.h, SHI);
            u.u = w6; alo = dot2sel(alo, u.h, SLO); ahi = dot2sel(ahi, u.h, SHI);
            u.u = w7; alo = dot2sel(alo, u.h, SLO); ahi = dot2sel(ahi, u.h, SHI);
        }
        for (; i < end; i++) {
            U32H2 u; u.u = feat[(size_t)ssrc[i] * P + lane];
            alo = dot2sel(alo, u.h, SLO); ahi = dot2sel(ahi, u.h, SHI);
        }
    }
    float ic = (n > 0) ? 1.0f / (float)n : 0.0f;
    mean[(size_t)g * P + lane] = pk2(alo * ic, ahi * ic);
}

#define G1 (N_TP * 32)
#define G2 (G1 + N_FM * 32)
#define G3 (G2 + N_FM * 16)
#define G4 (G3 + N_SM * 16)
#define G5 (G4 + N_FM * 16)

__global__ void __launch_bounds__(256)
gather_all(const int* __restrict__ el_beg, const int* __restrict__ el_end,
           const int* __restrict__ so_all,
           const unsigned* __restrict__ x_fm_f, const unsigned* __restrict__ pe_f,
           unsigned* __restrict__ mean_qoq, unsigned* __restrict__ mean_cp,
           unsigned* __restrict__ mean_rb, unsigned* __restrict__ mean_bp,
           unsigned* __restrict__ mean_cd) {
    int gid = blockIdx.x * blockDim.x + threadIdx.x;
    if (gid < G1) {
        gather_one<5, 16>(gid >> 5, gid & 31, el_beg + EL_BP, el_end + EL_BP, so_all, x_fm_f, mean_bp);
    } else if (gid < G2) {
        int i = gid - G1;
        gather_one<5, 16>(i >> 5, i & 31, el_beg + EL_QOQ, el_end + EL_QOQ, so_all, x_fm_f, mean_qoq);
    } else if (gid < G3) {
        int i = gid - G2;
        gather_one<4, 8>(i >> 4, i & 15, el_beg + EL_CP, el_end + EL_CP, so_all, pe_f, mean_cp);
    } else if (gid < G4) {
        int i = gid - G3;
        gather_one<4, 8>(i >> 4, i & 15, el_beg + EL_CD, el_end + EL_CD, so_all, pe_f, mean_cd);
    } else if (gid < G5) {
        int i = gid - G4;
        gather_one<4, 16>(i >> 4, i & 15, el_beg + EL_RB, el_end + EL_RB, so_all, pe_f, mean_rb);
    }
}

// ---------------------------------------------------------------- MFMA row kernels
// A-frag (16x32 f16): lane holds row=(lane&15), k=(lane>>4)*8..+7 -> contiguous uint4 at
//   u32 off = ks*16 + (lane>>4)*4 within the row. B-frag staged in LDS frag-major.
// C-frag: col=lane&15, row=(lane>>4)*4+reg  [verified layout, learn_hip m89]
// Column sums: block-level LDS reduce -> one 128-float partial per block (NO atomics).

__global__ void __launch_bounds__(256)
fm_mfma(const unsigned* __restrict__ mq, const unsigned* __restrict__ mc,
        const unsigned* __restrict__ mr, const unsigned* __restrict__ xf,
        const unsigned* __restrict__ wfrag, const float* __restrict__ bias,
        const float* __restrict__ ln_g, const float* __restrict__ ln_b,
        float* __restrict__ part) {
    __shared__ uint4 wlds[48 * 64];  // 48 KB
    const int tid = threadIdx.x, lane = tid & 63, wid = tid >> 6;
    for (int i = tid; i < 48 * 64; i += 256) wlds[i] = ((const uint4*)wfrag)[i];
    const int c0 = lane & 15, ko = lane >> 4;
    float bias_[8], g_[8], b_[8], colacc[8];
#pragma unroll
    for (int nt = 0; nt < 8; nt++) {
        int c = nt * 16 + c0;
        bias_[nt] = bias[c]; g_[nt] = ln_g[c]; b_[nt] = ln_b[c]; colacc[nt] = 0.0f;
    }
    __syncthreads();
    const f32x4_t zero = {0.0f, 0.0f, 0.0f, 0.0f};
    const int ntiles = N_FM / 16;
    for (int tile = blockIdx.x * 4 + wid; tile < ntiles; tile += gridDim.x * 4) {
        const size_t row = (size_t)tile * 16 + c0;
        uint4 av[6];
        av[0] = ((const uint4*)mq)[row * 8 + ko];
        av[1] = ((const uint4*)mq)[row * 8 + 4 + ko];
        av[2] = ((const uint4*)mc)[row * 4 + ko];
        av[3] = ((const uint4*)mr)[row * 4 + ko];
        av[4] = ((const uint4*)xf)[row * 8 + ko];
        av[5] = ((const uint4*)xf)[row * 8 + 4 + ko];
        f32x4_t acc[8];
#pragma unroll
        for (int nt = 0; nt < 8; nt++) acc[nt] = zero;
#pragma unroll
        for (int ks = 0; ks < 6; ks++) {
            f16x8_t af = as_h8(av[ks]);
#pragma unroll
            for (int nt = 0; nt < 8; nt++)
                acc[nt] = __builtin_amdgcn_mfma_f32_16x16x32_f16(
                    af, as_h8(wlds[(ks * 8 + nt) * 64 + lane]), acc[nt], 0, 0, 0);
        }
#pragma unroll
        for (int r = 0; r < 4; r++) {
            float yv[8]; float s = 0.0f, q = 0.0f;
#pragma unroll
            for (int nt = 0; nt < 8; nt++) {
                float y = (acc[nt][r] + bias_[nt]) * (1.0f / 3.0f);
                yv[nt] = y; s += y; q += y * y;
            }
#pragma unroll
            for (int off = 1; off < 16; off <<= 1) { s += __shfl_xor(s, off); q += __shfl_xor(q, off); }
            float mu = s * (1.0f / 128.0f);
            float var = fmaxf(q * (1.0f / 128.0f) - mu * mu, 0.0f);
            float rs = rsqrtf(var + 1e-5f);
#pragma unroll
            for (int nt = 0; nt < 8; nt++)
                colacc[nt] += fmaxf((yv[nt] - mu) * rs * g_[nt] + b_[nt], 0.0f);
        }
    }
#pragma unroll
    for (int nt = 0; nt < 8; nt++) {
        colacc[nt] += __shfl_xor(colacc[nt], 16);
        colacc[nt] += __shfl_xor(colacc[nt], 32);
    }
    __syncthreads();  // all waves done with wlds; reuse as reduction scratch
    float* sred = (float*)wlds;
    if (lane < 16) {
#pragma unroll
        for (int nt = 0; nt < 8; nt++) sred[wid * 128 + nt * 16 + lane] = colacc[nt];
    }
    __syncthreads();
    if (tid < 128)
        part[(size_t)blockIdx.x * 128 + tid] =
            sred[tid] + sred[128 + tid] + sred[256 + tid] + sred[384 + tid];
}

template <int KSA, int KSB>
__global__ void __launch_bounds__(256)
rows_mfma(int ntiles, const unsigned* __restrict__ mA, const unsigned* __restrict__ xB,
          const unsigned* __restrict__ wfrag, const float* __restrict__ bl,
          const float* __restrict__ ln_g, const float* __restrict__ ln_b,
          float* __restrict__ part) {
    constexpr int KS = KSA + KSB;
    __shared__ uint4 wlds[KS * 8 * 64];
    const int tid = threadIdx.x, lane = tid & 63, wid = tid >> 6;
    for (int i = tid; i < KS * 8 * 64; i += 256) wlds[i] = ((const uint4*)wfrag)[i];
    const int c0 = lane & 15, ko = lane >> 4;
    float bias_[8], g_[8], b_[8], colacc[8];
#pragma unroll
    for (int nt = 0; nt < 8; nt++) {
        int c = nt * 16 + c0;
        bias_[nt] = bl[c]; g_[nt] = ln_g[c]; b_[nt] = ln_b[c]; colacc[nt] = 0.0f;
    }
    __syncthreads();
    const f32x4_t zero = {0.0f, 0.0f, 0.0f, 0.0f};
    for (int tile = blockIdx.x * 4 + wid; tile < ntiles; tile += gridDim.x * 4) {
        const size_t row = (size_t)tile * 16 + c0;
        uint4 av[KS];
#pragma unroll
        for (int ks = 0; ks < KSA; ks++) av[ks] = ((const uint4*)mA)[row * (KSA * 4) + ks * 4 + ko];
#pragma unroll
        for (int ks = 0; ks < KSB; ks++) av[KSA + ks] = ((const uint4*)xB)[row * (KSB * 4) + ks * 4 + ko];
        f32x4_t acc[8];
#pragma unroll
        for (int nt = 0; nt < 8; nt++) acc[nt] = zero;
#pragma unroll
        for (int ks = 0; ks < KS; ks++) {
            f16x8_t af = as_h8(av[ks]);
#pragma unroll
            for (int nt = 0; nt < 8; nt++)
                acc[nt] = __builtin_amdgcn_mfma_f32_16x16x32_f16(
                    af, as_h8(wlds[(ks * 8 + nt) * 64 + lane]), acc[nt], 0, 0, 0);
        }
#pragma unroll
        for (int r = 0; r < 4; r++) {
            float yv[8]; float s = 0.0f, q = 0.0f;
#pragma unroll
            for (int nt = 0; nt < 8; nt++) {
                float y = acc[nt][r] + bias_[nt];
                yv[nt] = y; s += y; q += y * y;
            }
#pragma unroll
            for (int off = 1; off < 16; off <<= 1) { s += __shfl_xor(s, off); q += __shfl_xor(q, off); }
            float mu = s * (1.0f / 128.0f);
            float var = fmaxf(q * (1.0f / 128.0f) - mu * mu, 0.0f);
            float rs = rsqrtf(var + 1e-5f);
#pragma unroll
            for (int nt = 0; nt < 8; nt++)
                colacc[nt] += fmaxf((yv[nt] - mu) * rs * g_[nt] + b_[nt], 0.0f);
        }
    }
#pragma unroll
    for (int nt = 0; nt < 8; nt++) {
        colacc[nt] += __shfl_xor(colacc[nt], 16);
        colacc[nt] += __shfl_xor(colacc[nt], 32);
    }
    __syncthreads();  // all waves done with wlds; reuse as reduction scratch
    float* sred = (float*)wlds;
    if (lane < 16) {
#pragma unroll
        for (int nt = 0; nt < 8; nt++) sred[wid * 128 + nt * 16 + lane] = colacc[nt];
    }
    __syncthreads();
    if (tid < 128)
        part[(size_t)blockIdx.x * 128 + tid] =
            sred[tid] + sred[128 + tid] + sred[256 + tid] + sred[384 + tid];
}

// ---------------------------------------------------------------- partial-sum reduction (replaces atomics)
__global__ void __launch_bounds__(512)
reduce_cols(const float* __restrict__ part, float* __restrict__ colsum) {
    __shared__ float lds[512];
    const int t = threadIdx.x, col = t & 127, sl = t >> 7;
    int cnt, srcoff, dst;
    if (blockIdx.x == 0)      { cnt = GRID_FM; srcoff = 0;                         dst = 0;   }
    else if (blockIdx.x == 1) { cnt = GRID_TP; srcoff = GRID_FM * 128;             dst = 128; }
    else                      { cnt = GRID_SM; srcoff = (GRID_FM + GRID_TP) * 128; dst = 256; }
    float a = 0.0f;
    for (int i = sl; i < cnt; i += 4) a += part[srcoff + i * 128 + col];
    lds[t] = a;
    __syncthreads();
    if (t < 128) colsum[dst + t] = lds[t] + lds[128 + t] + lds[256 + t] + lds[384 + t];
}

// ---------------------------------------------------------------- head MLP -> scalar (split-K)
__global__ void head_kernel(const float* __restrict__ colsum, const float* __restrict__ gf,
                            const float* __restrict__ W1, const float* __restrict__ b1,
                            const float* __restrict__ W2, const float* __restrict__ b2,
                            float* __restrict__ out) {
    __shared__ float h[448];
    __shared__ float sh[512];
    __shared__ float h1[64];
    int t = threadIdx.x;  // 512 threads
    if (t < 128) h[t] = colsum[t] * (1.0f / N_FM);
    else if (t < 256) h[t] = colsum[t] * (1.0f / N_TP);
    else if (t < 384) h[t] = colsum[t] * (1.0f / N_SM);
    else if (t < 448) h[t] = gf[t - 384];
    __syncthreads();
    {
        int col = t & 63, slice = t >> 6;
        float a = 0.0f;
        for (int k = slice * 56; k < slice * 56 + 56; k++) a += h[k] * W1[k * 64 + col];
        sh[slice * 64 + col] = a;
    }
    __syncthreads();
    if (t < 64) {
        float a = b1[t];
#pragma unroll
        for (int s = 0; s < 8; s++) a += sh[s * 64 + t];
        h1[t] = fmaxf(a, 0.0f);
    }
    __syncthreads();
    if (t < 64) {
        float p = h1[t] * W2[t];
#pragma unroll
        for (int off = 1; off < 64; off <<= 1) p += __shfl_xor(p, off);
        if (t == 0) out[0] = p + b2[0];
    }
}

extern "C" void kernel_launch(void* const* d_in, const int* in_sizes, int n_in,
                              void* d_out, int out_size, void* d_ws, size_t ws_size,
                              hipStream_t stream) {
    const float* x_fm = (const float*)d_in[0];
    const float* x_sm = (const float*)d_in[1];
    const float* period_vol = (const float*)d_in[2];
    const float* gf = (const float*)d_in[3];
    const float* pe_table = (const float*)d_in[4];
    const int* qoq_src = (const int*)d_in[5];
    const int* qoq_dst = (const int*)d_in[6];
    const int* bp_src = (const int*)d_in[7];
    const int* bp_dst = (const int*)d_in[8];
    const int* cp_src = (const int*)d_in[9];
    const int* cp_dst = (const int*)d_in[10];
    const int* cd_src = (const int*)d_in[11];
    const int* cd_dst = (const int*)d_in[12];
    const int* rb_src = (const int*)d_in[13];
    const int* rb_dst = (const int*)d_in[14];
    const float* qoq_Wl = (const float*)d_in[15];
    const float* qoq_bl = (const float*)d_in[16];
    const float* qoq_Wr = (const float*)d_in[17];
    const float* bp_Wl = (const float*)d_in[18];
    const float* bp_bl = (const float*)d_in[19];
    const float* bp_Wr = (const float*)d_in[20];
    const float* cp_Wl = (const float*)d_in[21];
    const float* cp_bl = (const float*)d_in[22];
    const float* cp_Wr = (const float*)d_in[23];
    const float* cd_Wl = (const float*)d_in[24];
    const float* cd_bl = (const float*)d_in[25];
    const float* cd_Wr = (const float*)d_in[26];
    const float* rb_Wl = (const float*)d_in[27];
    const float* rb_bl = (const float*)d_in[28];
    const float* rb_Wr = (const float*)d_in[29];
    const float* ln_fm_g = (const float*)d_in[30];
    const float* ln_fm_b = (const float*)d_in[31];
    const float* ln_tp_g = (const float*)d_in[32];
    const float* ln_tp_b = (const float*)d_in[33];
    const float* ln_sm_g = (const float*)d_in[34];
    const float* ln_sm_b = (const float*)d_in[35];
    const float* head_W1 = (const float*)d_in[36];
    const float* head_b1 = (const float*)d_in[37];
    const float* head_W2 = (const float*)d_in[38];
    const float* head_b2 = (const float*)d_in[39];

    // workspace (4-byte words); zero region: bucket cursors + colsum
    unsigned* wsu = (unsigned*)d_ws;
    size_t off = 0;
    int* bwork = (int*)(wsu + off); off += NBUCK;
    float* colsum = (float*)(wsu + off); off += 384;
    size_t zero_words = off;
    off = (off + 3) & ~(size_t)3;  // 16B-align everything downstream (uint4 loads)
    unsigned* pairs = wsu + off; off += PAIRS_CAP;
    int* so_all = (int*)(wsu + off); off += PAIRS_CAP;
    int* el_beg = (int*)(wsu + off); off += NTOT;
    int* el_end = (int*)(wsu + off); off += NTOT;
    unsigned* mean_qoq = wsu + off; off += (size_t)N_FM * 32;
    unsigned* mean_cp  = wsu + off; off += (size_t)N_FM * 16;
    unsigned* mean_rb  = wsu + off; off += (size_t)N_FM * 16;
    unsigned* mean_bp  = wsu + off; off += (size_t)N_TP * 32;
    unsigned* mean_cd  = wsu + off; off += (size_t)N_SM * 16;
    unsigned* pe_f     = wsu + off; off += (size_t)N_TP * 16;
    unsigned* x_fm_f   = wsu + off; off += (size_t)N_FM * 32;
    unsigned* x_sm_f   = wsu + off; off += (size_t)N_SM * 16;
    unsigned* wf_fm    = wsu + off; off += 12288;
    unsigned* wf_tp    = wsu + off; off += 6144;
    unsigned* wf_sm    = wsu + off; off += 4096;
    float* bias_fm     = (float*)(wsu + off); off += 128;

    // per-block column partials alias the (dead-after-esort) pairs buffer
    float* part_fm = (float*)pairs;                 // GRID_FM*128
    float* part_tp = part_fm + GRID_FM * 128;       // GRID_TP*128
    float* part_sm = part_tp + GRID_TP * 128;       // GRID_SM*128

    hipMemsetAsync(d_ws, 0, zero_words * 4, stream);

    pack_all<<<(R7 + 255) / 256, 256, 0, stream>>>(
        x_fm, x_sm, pe_table, period_vol, qoq_Wl, cp_Wl, rb_Wl, qoq_Wr, cp_Wr, rb_Wr,
        bp_Wl, bp_Wr, cd_Wl, cd_Wr, qoq_bl, cp_bl, rb_bl,
        x_fm_f, x_sm_f, pe_f, wf_fm, wf_tp, wf_sm, bias_fm);

    EdgePtrs EP{qoq_src, qoq_dst, cp_src, cp_dst, rb_src, rb_dst, bp_src, bp_dst, cd_src, cd_dst};

    bin_kernel<<<NCHUNK, 256, 0, stream>>>(EP, bwork, pairs);
    esort<<<NBUCK, 256, 0, stream>>>(bwork, pairs, so_all, el_beg, el_end);
    gather_all<<<(G5 + 255) / 256, 256, 0, stream>>>(el_beg, el_end, so_all, x_fm_f, pe_f,
                                                     mean_qoq, mean_cp, mean_rb, mean_bp, mean_cd);

    // MFMA row kernels (fused GEMM + LN + ReLU + per-block column partials)
    fm_mfma<<<GRID_FM, 256, 0, stream>>>(mean_qoq, mean_cp, mean_rb, x_fm_f, wf_fm,
                                         bias_fm, ln_fm_g, ln_fm_b, part_fm);
    rows_mfma<2, 1><<<GRID_TP, 256, 0, stream>>>(N_TP / 16, mean_bp, pe_f, wf_tp,
                                                 bp_bl, ln_tp_g, ln_tp_b, part_tp);
    rows_mfma<1, 1><<<GRID_SM, 256, 0, stream>>>(N_SM / 16, mean_cd, x_sm_f, wf_sm,
                                                 cd_bl, ln_sm_g, ln_sm_b, part_sm);

    reduce_cols<<<3, 512, 0, stream>>>(part_fm, colsum);

    head_kernel<<<1, 512, 0, stream>>>(colsum, gf, head_W1, head_b1, head_W2, head_b2,
                                       (float*)d_out);
}

// Round 14
// 426.509 us; speedup vs baseline: 1.0460x; 1.0237x over previous
//
#include <hip/hip_runtime.h>
#include <hip/hip_fp16.h>

#define N_FM 100000
#define N_TP 4096
#define N_SM 100000
#define HID 128
#define E_QOQ 1000000
#define E_BP 1000000
#define E_CP 500000
#define E_CD 500000
#define E_RB 1000000
#define E_TOT 4000000

// global edge-id order: qoq | cp | rb | bp | cd
#define EO_CP  1000000
#define EO_RB  1500000
#define EO_BP  2500000
#define EO_CD  3500000

// element space (concatenated): qoq | cp | rb | bp | cd
#define EL_QOQ 0
#define EL_CP  (N_FM)
#define EL_RB  (2 * N_FM)
#define EL_BP  (3 * N_FM)
#define EL_CD  (3 * N_FM + N_TP)
#define NTOT   (3 * N_FM + N_TP + N_SM)

// buckets: qoq 128 elems (shift 7) | cp/rb/cd 256 (shift 8) | bp 32 (shift 5)
#define BB_QOQ 0
#define BB_CP  782
#define BB_RB  1173
#define BB_BP  1564
#define BB_CD  1692
#define NBUCK  2083
// CHUNK=4096: measured optimum of the bin tradeoff (4096: 429.8us total;
// 8192: 436.6; 16384: 107us bin dispatch, latency-starved).
#define CHUNK  4096
#define NCHUNK ((E_TOT + CHUNK - 1) / CHUNK)
#define EPB    (CHUNK / 256)

#define PAIRS_CAP 5784064

// row-kernel grids (must match partial-buffer layout)
#define GRID_FM 768
#define GRID_TP 64
#define GRID_SM 1024

__device__ __forceinline__ int bucket_base(int b) {
    if (b < BB_CP) return b * 2048;
    if (b < BB_RB) return 1601536 + (b - BB_CP) * 2048;
    if (b < BB_BP) return 2402304 + (b - BB_RB) * 3584;
    if (b < BB_CD) return 3803648 + (b - BB_BP) * 9216;
    return 4983296 + (b - BB_CD) * 2048;
}

typedef _Float16 h2 __attribute__((ext_vector_type(2)));
typedef _Float16 f16x8_t __attribute__((ext_vector_type(8)));
typedef float f32x4_t __attribute__((ext_vector_type(4)));

union U32H2 { unsigned u; h2 h; };
union U4H8 { uint4 u; f16x8_t h; };

#if defined(__has_builtin)
#if __has_builtin(__builtin_amdgcn_fdot2)
#define HAVE_FDOT2 1
#endif
#endif

__device__ __forceinline__ unsigned pk2(float a, float b) {
    U32H2 x; x.h = h2{(_Float16)a, (_Float16)b}; return x.u;
}
__device__ __forceinline__ f16x8_t as_h8(uint4 v) { U4H8 x; x.u = v; return x.h; }

// acc += v . sel  (one v_dot2_f32_f16 instead of 2x cvt + 2x add)
__device__ __forceinline__ float dot2sel(float acc, h2 v, h2 sel) {
#ifdef HAVE_FDOT2
    return __builtin_amdgcn_fdot2(v, sel, acc, false);
#else
    return acc + (float)v[0] * (float)sel[0] + (float)v[1] * (float)sel[1];
#endif
}

// ---------------------------------------------------------------- unified pack kernel
// feature sections vectorized float4 (16B/lane)
#define R1 (N_FM * 16)
#define R2 (R1 + N_SM * 8)
#define R3 (R2 + N_TP * 8)
// MFMA-frag-major weights: element j -> f=j>>8 (frag = ks*8+nt), lane=(j>>2)&63, jj=j&3
//   p (h2 pair row) = (f>>3)*16 + ((lane>>4)<<2) + jj ; c = (f&7)*16 + (lane&15)
#define R4 (R3 + 12288)   // fm: 6 ks * 8 nt * 256
#define R5 (R4 + 6144)    // tp: 3 ks * 8 nt * 256
#define R6 (R5 + 4096)    // sm: 2 ks * 8 nt * 256
#define R7 (R6 + 128)     // combined fm bias

__device__ __forceinline__ unsigned pack_pair(const float* W, int p, int c) {
    return pk2(W[(2 * p) * HID + c], W[(2 * p + 1) * HID + c]);
}

__global__ void pack_all(const float* __restrict__ x_fm, const float* __restrict__ x_sm,
                         const float* __restrict__ pe_table, const float* __restrict__ pvol,
                         const float* __restrict__ qoq_Wl, const float* __restrict__ cp_Wl,
                         const float* __restrict__ rb_Wl, const float* __restrict__ qoq_Wr,
                         const float* __restrict__ cp_Wr, const float* __restrict__ rb_Wr,
                         const float* __restrict__ bp_Wl, const float* __restrict__ bp_Wr,
                         const float* __restrict__ cd_Wl, const float* __restrict__ cd_Wr,
                         const float* __restrict__ qoq_bl, const float* __restrict__ cp_bl,
                         const float* __restrict__ rb_bl,
                         unsigned* __restrict__ x_fm_f, unsigned* __restrict__ x_sm_f,
                         unsigned* __restrict__ pe_f, unsigned* __restrict__ wf_fm,
                         unsigned* __restrict__ wf_tp, unsigned* __restrict__ wf_sm,
                         float* __restrict__ bias_fm) {
    int gid = blockIdx.x * blockDim.x + threadIdx.x;
    if (gid < R1) {
        float4 t = ((const float4*)x_fm)[gid];
        uint2 o; o.x = pk2(t.x, t.y); o.y = pk2(t.z, t.w);
        ((uint2*)x_fm_f)[gid] = o;
    } else if (gid < R2) {
        int i = gid - R1;
        float4 t = ((const float4*)x_sm)[i];
        uint2 o; o.x = pk2(t.x, t.y); o.y = pk2(t.z, t.w);
        ((uint2*)x_sm_f)[i] = o;
    } else if (gid < R3) {
        int i = gid - R2;
        float4 t = ((const float4*)pe_table)[i];
        float v = pvol[i >> 3];
        uint2 o; o.x = pk2(t.x * v, t.y * v); o.y = pk2(t.z * v, t.w * v);
        ((uint2*)pe_f)[i] = o;
    } else if (gid < R4) {
        int j = gid - R3;
        int f = j >> 8, lr = (j >> 2) & 63, jj = j & 3;
        int p = (f >> 3) * 16 + ((lr >> 4) << 2) + jj;
        int c = (f & 7) * 16 + (lr & 15);
        unsigned v;
        if (p < 32) v = pack_pair(qoq_Wl, p, c);
        else if (p < 48) v = pack_pair(cp_Wl, p - 32, c);
        else if (p < 64) v = pack_pair(rb_Wl, p - 48, c);
        else {
            int pp = p - 64;
            float u0 = qoq_Wr[(2 * pp) * HID + c] + cp_Wr[(2 * pp) * HID + c] + rb_Wr[(2 * pp) * HID + c];
            float u1 = qoq_Wr[(2 * pp + 1) * HID + c] + cp_Wr[(2 * pp + 1) * HID + c] + rb_Wr[(2 * pp + 1) * HID + c];
            v = pk2(u0, u1);
        }
        wf_fm[j] = v;
    } else if (gid < R5) {
        int j = gid - R4;
        int f = j >> 8, lr = (j >> 2) & 63, jj = j & 3;
        int p = (f >> 3) * 16 + ((lr >> 4) << 2) + jj;
        int c = (f & 7) * 16 + (lr & 15);
        wf_tp[j] = (p < 32) ? pack_pair(bp_Wl, p, c) : pack_pair(bp_Wr, p - 32, c);
    } else if (gid < R6) {
        int j = gid - R5;
        int f = j >> 8, lr = (j >> 2) & 63, jj = j & 3;
        int p = (f >> 3) * 16 + ((lr >> 4) << 2) + jj;
        int c = (f & 7) * 16 + (lr & 15);
        wf_sm[j] = (p < 16) ? pack_pair(cd_Wl, p, c) : pack_pair(cd_Wr, p - 16, c);
    } else if (gid < R7) {
        int c = gid - R6;
        bias_fm[c] = qoq_bl[c] + cp_bl[c] + rb_bl[c];
    }
}

// ---------------------------------------------------------------- edge decode (branchless: selects, then ONE load)
struct EdgePtrs {
    const int *qs, *qd, *cs, *cd_, *rs, *rd, *bs, *bd, *ds, *dd;
};

template <bool NEED_SRC>
__device__ __forceinline__ void edge_decode(const EdgePtrs& P, int e, int& bucket, int& dl, int& src) {
    const int* dp = P.qd; const int* sp = P.qs;
    int i = e, bb = BB_QOQ, sh = 7;
    if (e >= EO_CP) { i = e - EO_CP; dp = P.cd_; sp = P.cs; bb = BB_CP; sh = 8; }
    if (e >= EO_RB) { i = e - EO_RB; dp = P.rd;  sp = P.rs; bb = BB_RB; sh = 8; }
    if (e >= EO_BP) { i = e - EO_BP; dp = P.bd;  sp = P.bs; bb = BB_BP; sh = 5; }
    if (e >= EO_CD) { i = e - EO_CD; dp = P.dd;  sp = P.ds; bb = BB_CD; sh = 8; }
    int d = dp[i];
    bucket = bb + (d >> sh);
    dl = d & ((1 << sh) - 1);
    if (NEED_SRC) src = sp[i];
}

// ---------------------------------------------------------------- bin: block-reserved bucket scatter
// Single decode pass: (bucket|dl, src) cached in registers across both phases.
// Block-reserved bucket slices keep pairs writes CONTIGUOUS per block (r8:
// element-ordered direct scatter costs 16x write amp).
__global__ void __launch_bounds__(256) bin_kernel(EdgePtrs P, int* __restrict__ bwork,
                                                  unsigned* __restrict__ pairs) {
    __shared__ int lh[NBUCK];
    const int tid = threadIdx.x;
    for (int i = tid; i < NBUCK; i += 256) lh[i] = 0;
    __syncthreads();
    const int base = blockIdx.x * CHUNK;
    const int lim = min(base + CHUNK, E_TOT);
    unsigned ebd[EPB]; int esr[EPB];
#pragma unroll
    for (int j = 0; j < EPB; j++) {
        int e = base + tid + j * 256;
        if (e < lim) {
            int b, dl, s;
            edge_decode<true>(P, e, b, dl, s);
            ebd[j] = ((unsigned)b << 8) | (unsigned)dl;   // b < 4096, dl < 256
            esr[j] = s;
            atomicAdd(&lh[b], 1);
        }
    }
    __syncthreads();
#pragma unroll
    for (int u = 0; u < (NBUCK + 255) / 256; u++) {
        int b = tid + u * 256;
        if (b < NBUCK) {
            int c = lh[b];
            lh[b] = c ? bucket_base(b) + atomicAdd(&bwork[b], c) : 0;
        }
    }
    __syncthreads();
#pragma unroll
    for (int j = 0; j < EPB; j++) {
        int e = base + tid + j * 256;
        if (e < lim) {
            int b = (int)(ebd[j] >> 8);
            int pos = atomicAdd(&lh[b], 1);
            pairs[pos] = ((ebd[j] & 255u) << 24) | (unsigned)esr[j];
        }
    }
}

// ---------------------------------------------------------------- esort: per-bucket LDS counting sort by element
// Wave-shuffle scan (6 shfl steps + 2 barriers) replaces the 16-barrier LDS scan.
__global__ void __launch_bounds__(256) esort(const int* __restrict__ bwork,
                                             const unsigned* __restrict__ pairs,
                                             int* __restrict__ so,
                                             int* __restrict__ el_beg, int* __restrict__ el_end) {
    __shared__ int hist[256];
    __shared__ int wsum[4];
    __shared__ int so_lds[9216];  // max bucket capacity (bp)
    const int b = blockIdx.x;
    const int tid = threadIdx.x;
    const int lane = tid & 63, wv = tid >> 6;
    int beg = bucket_base(b);
    int end = beg + bwork[b];
    int egbase, ne;
    if (b < BB_CP)      { int e0 = (b - BB_QOQ) << 7; egbase = EL_QOQ + e0; ne = min(128, N_FM - e0); }
    else if (b < BB_RB) { int e0 = (b - BB_CP) << 8;  egbase = EL_CP + e0;  ne = min(256, N_FM - e0); }
    else if (b < BB_BP) { int e0 = (b - BB_RB) << 8;  egbase = EL_RB + e0;  ne = min(256, N_FM - e0); }
    else if (b < BB_CD) { int e0 = (b - BB_BP) << 5;  egbase = EL_BP + e0;  ne = min(32, N_TP - e0); }
    else                { int e0 = (b - BB_CD) << 8;  egbase = EL_CD + e0;  ne = min(256, N_SM - e0); }
    hist[tid] = 0;
    __syncthreads();
    for (int e = beg + tid; e < end; e += 256)
        atomicAdd(&hist[pairs[e] >> 24], 1);
    __syncthreads();
    int v = hist[tid];
    // inclusive wave scan
    int x = v;
#pragma unroll
    for (int off = 1; off < 64; off <<= 1) {
        int u = __shfl_up(x, off);
        if (lane >= off) x += u;
    }
    if (lane == 63) wsum[wv] = x;
    __syncthreads();
    int wbase = 0;
#pragma unroll
    for (int w = 0; w < 4; w++) wbase += (w < wv) ? wsum[w] : 0;
    int excl = wbase + x - v;
    if (tid < ne) {
        el_beg[egbase + tid] = beg + excl;
        el_end[egbase + tid] = beg + excl + v;
    }
    hist[tid] = excl;  // bucket-relative cursor
    __syncthreads();
    for (int e = beg + tid; e < end; e += 256) {
        unsigned pr = pairs[e];
        int dl = pr >> 24;
        int pos = atomicAdd(&hist[dl], 1);
        so_lds[pos] = (int)(pr & 0xFFFFFF);
    }
    __syncthreads();
    const int n = end - beg;
    for (int i = tid; i < n; i += 256) so[beg + i] = so_lds[i];
}

// ---------------------------------------------------------------- gather: element CSR, register fp32 accumulate
// Masked NPRO-slot prologue: ONE index stage + ONE fully-parallel feature stage
// covers deg<=NPRO (avg deg 10 / 5); overflow uses 8-deep continuation.
template <int LOGP, int NPRO>
__device__ __forceinline__ void gather_one(int g, int lane, const int* __restrict__ begs,
                                           const int* __restrict__ ends,
                                           const int* __restrict__ ssrc,
                                           const unsigned* __restrict__ feat,
                                           unsigned* __restrict__ mean) {
    const int P = 1 << LOGP;
    const h2 SLO = h2{(_Float16)1.0f, (_Float16)0.0f};
    const h2 SHI = h2{(_Float16)0.0f, (_Float16)1.0f};
    int beg = begs[g], end = ends[g];
    int n = end - beg;
    float alo = 0.0f, ahi = 0.0f;
    if (n > 0) {
        const int nm1 = n - 1;
        int s[NPRO];
#pragma unroll
        for (int j = 0; j < NPRO; j++) s[j] = ssrc[beg + min(j, nm1)];
        unsigned v[NPRO];
#pragma unroll
        for (int j = 0; j < NPRO; j++) v[j] = feat[(size_t)(unsigned)s[j] * P + lane];
#pragma unroll
        for (int j = 0; j < NPRO; j++) {
            U32H2 u; u.u = (j < n) ? v[j] : 0u;
            alo = dot2sel(alo, u.h, SLO); ahi = dot2sel(ahi, u.h, SHI);
        }
        int i = beg + NPRO;
        for (; i + 8 <= end; i += 8) {
            int t0 = ssrc[i],     t1 = ssrc[i + 1], t2 = ssrc[i + 2], t3 = ssrc[i + 3];
            int t4 = ssrc[i + 4], t5 = ssrc[i + 5], t6 = ssrc[i + 6], t7 = ssrc[i + 7];
            unsigned w0 = feat[(size_t)t0 * P + lane];
            unsigned w1 = feat[(size_t)t1 * P + lane];
            unsigned w2 = feat[(size_t)t2 * P + lane];
            unsigned w3 = feat[(size_t)t3 * P + lane];
            unsigned w4 = feat[(size_t)t4 * P + lane];
            unsigned w5 = feat[(size_t)t5 * P + lane];
            unsigned w6 = feat[(size_t)t6 * P + lane];
            unsigned w7 = feat[(size_t)t7 * P + lane];
            U32H2 u;
            u.u = w0; alo = dot2sel(alo, u.h, SLO); ahi = dot2sel(ahi, u.h, SHI);
            u.u = w1; alo = dot2sel(alo, u.h, SLO); ahi = dot2sel(ahi, u.h, SHI);
            u.u = w2; alo = dot2sel(alo, u.h, SLO); ahi = dot2sel(ahi, u.h, SHI);
            u.u = w3; alo = dot2sel(alo, u.h, SLO); ahi = dot2sel(ahi, u.h, SHI);
            u.u = w4; alo = dot2sel(alo, u.h, SLO); ahi = dot2sel(ahi, u.h, SHI);
            u.u = w5; alo = dot2sel(alo, u.h, SLO); ahi = dot2sel(ahi, u.h, SHI);
            u.u = w6; alo = dot2sel(alo, u.h, SLO); ahi = dot2sel(ahi, u.h, SHI);
            u.u = w7; alo = dot2sel(alo, u.h, SLO); ahi = dot2sel(ahi, u.h, SHI);
        }
        for (; i < end; i++) {
            U32H2 u; u.u = feat[(size_t)ssrc[i] * P + lane];
            alo = dot2sel(alo, u.h, SLO); ahi = dot2sel(ahi, u.h, SHI);
        }
    }
    float ic = (n > 0) ? 1.0f / (float)n : 0.0f;
    mean[(size_t)g * P + lane] = pk2(alo * ic, ahi * ic);
}

#define G1 (N_TP * 32)
#define G2 (G1 + N_FM * 32)
#define G3 (G2 + N_FM * 16)
#define G4 (G3 + N_SM * 16)
#define G5 (G4 + N_FM * 16)

__global__ void __launch_bounds__(256)
gather_all(const int* __restrict__ el_beg, const int* __restrict__ el_end,
           const int* __restrict__ so_all,
           const unsigned* __restrict__ x_fm_f, const unsigned* __restrict__ pe_f,
           unsigned* __restrict__ mean_qoq, unsigned* __restrict__ mean_cp,
           unsigned* __restrict__ mean_rb, unsigned* __restrict__ mean_bp,
           unsigned* __restrict__ mean_cd) {
    int gid = blockIdx.x * blockDim.x + threadIdx.x;
    if (gid < G1) {
        gather_one<5, 16>(gid >> 5, gid & 31, el_beg + EL_BP, el_end + EL_BP, so_all, x_fm_f, mean_bp);
    } else if (gid < G2) {
        int i = gid - G1;
        gather_one<5, 16>(i >> 5, i & 31, el_beg + EL_QOQ, el_end + EL_QOQ, so_all, x_fm_f, mean_qoq);
    } else if (gid < G3) {
        int i = gid - G2;
        gather_one<4, 8>(i >> 4, i & 15, el_beg + EL_CP, el_end + EL_CP, so_all, pe_f, mean_cp);
    } else if (gid < G4) {
        int i = gid - G3;
        gather_one<4, 8>(i >> 4, i & 15, el_beg + EL_CD, el_end + EL_CD, so_all, pe_f, mean_cd);
    } else if (gid < G5) {
        int i = gid - G4;
        gather_one<4, 16>(i >> 4, i & 15, el_beg + EL_RB, el_end + EL_RB, so_all, pe_f, mean_rb);
    }
}

// ---------------------------------------------------------------- MFMA row kernels
// A-frag (16x32 f16): lane holds row=(lane&15), k=(lane>>4)*8..+7 -> contiguous uint4 at
//   u32 off = ks*16 + (lane>>4)*4 within the row. B-frag staged in LDS frag-major.
// C-frag: col=lane&15, row=(lane>>4)*4+reg  [verified layout, learn_hip m89]
// Column sums: block-level LDS reduce -> one 128-float partial per block (NO atomics).

__global__ void __launch_bounds__(256)
fm_mfma(const unsigned* __restrict__ mq, const unsigned* __restrict__ mc,
        const unsigned* __restrict__ mr, const unsigned* __restrict__ xf,
        const unsigned* __restrict__ wfrag, const float* __restrict__ bias,
        const float* __restrict__ ln_g, const float* __restrict__ ln_b,
        float* __restrict__ part) {
    __shared__ uint4 wlds[48 * 64];  // 48 KB
    const int tid = threadIdx.x, lane = tid & 63, wid = tid >> 6;
    for (int i = tid; i < 48 * 64; i += 256) wlds[i] = ((const uint4*)wfrag)[i];
    const int c0 = lane & 15, ko = lane >> 4;
    float bias_[8], g_[8], b_[8], colacc[8];
#pragma unroll
    for (int nt = 0; nt < 8; nt++) {
        int c = nt * 16 + c0;
        bias_[nt] = bias[c]; g_[nt] = ln_g[c]; b_[nt] = ln_b[c]; colacc[nt] = 0.0f;
    }
    __syncthreads();
    const f32x4_t zero = {0.0f, 0.0f, 0.0f, 0.0f};
    const int ntiles = N_FM / 16;
    for (int tile = blockIdx.x * 4 + wid; tile < ntiles; tile += gridDim.x * 4) {
        const size_t row = (size_t)tile * 16 + c0;
        uint4 av[6];
        av[0] = ((const uint4*)mq)[row * 8 + ko];
        av[1] = ((const uint4*)mq)[row * 8 + 4 + ko];
        av[2] = ((const uint4*)mc)[row * 4 + ko];
        av[3] = ((const uint4*)mr)[row * 4 + ko];
        av[4] = ((const uint4*)xf)[row * 8 + ko];
        av[5] = ((const uint4*)xf)[row * 8 + 4 + ko];
        f32x4_t acc[8];
#pragma unroll
        for (int nt = 0; nt < 8; nt++) acc[nt] = zero;
#pragma unroll
        for (int ks = 0; ks < 6; ks++) {
            f16x8_t af = as_h8(av[ks]);
#pragma unroll
            for (int nt = 0; nt < 8; nt++)
                acc[nt] = __builtin_amdgcn_mfma_f32_16x16x32_f16(
                    af, as_h8(wlds[(ks * 8 + nt) * 64 + lane]), acc[nt], 0, 0, 0);
        }
#pragma unroll
        for (int r = 0; r < 4; r++) {
            float yv[8]; float s = 0.0f, q = 0.0f;
#pragma unroll
            for (int nt = 0; nt < 8; nt++) {
                float y = (acc[nt][r] + bias_[nt]) * (1.0f / 3.0f);
                yv[nt] = y; s += y; q += y * y;
            }
#pragma unroll
            for (int off = 1; off < 16; off <<= 1) { s += __shfl_xor(s, off); q += __shfl_xor(q, off); }
            float mu = s * (1.0f / 128.0f);
            float var = fmaxf(q * (1.0f / 128.0f) - mu * mu, 0.0f);
            float rs = rsqrtf(var + 1e-5f);
#pragma unroll
            for (int nt = 0; nt < 8; nt++)
                colacc[nt] += fmaxf((yv[nt] - mu) * rs * g_[nt] + b_[nt], 0.0f);
        }
    }
#pragma unroll
    for (int nt = 0; nt < 8; nt++) {
        colacc[nt] += __shfl_xor(colacc[nt], 16);
        colacc[nt] += __shfl_xor(colacc[nt], 32);
    }
    __syncthreads();  // all waves done with wlds; reuse as reduction scratch
    float* sred = (float*)wlds;
    if (lane < 16) {
#pragma unroll
        for (int nt = 0; nt < 8; nt++) sred[wid * 128 + nt * 16 + lane] = colacc[nt];
    }
    __syncthreads();
    if (tid < 128)
        part[(size_t)blockIdx.x * 128 + tid] =
            sred[tid] + sred[128 + tid] + sred[256 + tid] + sred[384 + tid];
}

template <int KSA, int KSB>
__global__ void __launch_bounds__(256)
rows_mfma(int ntiles, const unsigned* __restrict__ mA, const unsigned* __restrict__ xB,
          const unsigned* __restrict__ wfrag, const float* __restrict__ bl,
          const float* __restrict__ ln_g, const float* __restrict__ ln_b,
          float* __restrict__ part) {
    constexpr int KS = KSA + KSB;
    __shared__ uint4 wlds[KS * 8 * 64];
    const int tid = threadIdx.x, lane = tid & 63, wid = tid >> 6;
    for (int i = tid; i < KS * 8 * 64; i += 256) wlds[i] = ((const uint4*)wfrag)[i];
    const int c0 = lane & 15, ko = lane >> 4;
    float bias_[8], g_[8], b_[8], colacc[8];
#pragma unroll
    for (int nt = 0; nt < 8; nt++) {
        int c = nt * 16 + c0;
        bias_[nt] = bl[c]; g_[nt] = ln_g[c]; b_[nt] = ln_b[c]; colacc[nt] = 0.0f;
    }
    __syncthreads();
    const f32x4_t zero = {0.0f, 0.0f, 0.0f, 0.0f};
    for (int tile = blockIdx.x * 4 + wid; tile < ntiles; tile += gridDim.x * 4) {
        const size_t row = (size_t)tile * 16 + c0;
        uint4 av[KS];
#pragma unroll
        for (int ks = 0; ks < KSA; ks++) av[ks] = ((const uint4*)mA)[row * (KSA * 4) + ks * 4 + ko];
#pragma unroll
        for (int ks = 0; ks < KSB; ks++) av[KSA + ks] = ((const uint4*)xB)[row * (KSB * 4) + ks * 4 + ko];
        f32x4_t acc[8];
#pragma unroll
        for (int nt = 0; nt < 8; nt++) acc[nt] = zero;
#pragma unroll
        for (int ks = 0; ks < KS; ks++) {
            f16x8_t af = as_h8(av[ks]);
#pragma unroll
            for (int nt = 0; nt < 8; nt++)
                acc[nt] = __builtin_amdgcn_mfma_f32_16x16x32_f16(
                    af, as_h8(wlds[(ks * 8 + nt) * 64 + lane]), acc[nt], 0, 0, 0);
        }
#pragma unroll
        for (int r = 0; r < 4; r++) {
            float yv[8]; float s = 0.0f, q = 0.0f;
#pragma unroll
            for (int nt = 0; nt < 8; nt++) {
                float y = acc[nt][r] + bias_[nt];
                yv[nt] = y; s += y; q += y * y;
            }
#pragma unroll
            for (int off = 1; off < 16; off <<= 1) { s += __shfl_xor(s, off); q += __shfl_xor(q, off); }
            float mu = s * (1.0f / 128.0f);
            float var = fmaxf(q * (1.0f / 128.0f) - mu * mu, 0.0f);
            float rs = rsqrtf(var + 1e-5f);
#pragma unroll
            for (int nt = 0; nt < 8; nt++)
                colacc[nt] += fmaxf((yv[nt] - mu) * rs * g_[nt] + b_[nt], 0.0f);
        }
    }
#pragma unroll
    for (int nt = 0; nt < 8; nt++) {
        colacc[nt] += __shfl_xor(colacc[nt], 16);
        colacc[nt] += __shfl_xor(colacc[nt], 32);
    }
    __syncthreads();  // all waves done with wlds; reuse as reduction scratch
    float* sred = (float*)wlds;
    if (lane < 16) {
#pragma unroll
        for (int nt = 0; nt < 8; nt++) sred[wid * 128 + nt * 16 + lane] = colacc[nt];
    }
    __syncthreads();
    if (tid < 128)
        part[(size_t)blockIdx.x * 128 + tid] =
            sred[tid] + sred[128 + tid] + sred[256 + tid] + sred[384 + tid];
}

// ---------------------------------------------------------------- partial-sum reduction (replaces atomics)
__global__ void __launch_bounds__(512)
reduce_cols(const float* __restrict__ part, float* __restrict__ colsum) {
    __shared__ float lds[512];
    const int t = threadIdx.x, col = t & 127, sl = t >> 7;
    int cnt, srcoff, dst;
    if (blockIdx.x == 0)      { cnt = GRID_FM; srcoff = 0;                         dst = 0;   }
    else if (blockIdx.x == 1) { cnt = GRID_TP; srcoff = GRID_FM * 128;             dst = 128; }
    else                      { cnt = GRID_SM; srcoff = (GRID_FM + GRID_TP) * 128; dst = 256; }
    float a = 0.0f;
    for (int i = sl; i < cnt; i += 4) a += part[srcoff + i * 128 + col];
    lds[t] = a;
    __syncthreads();
    if (t < 128) colsum[dst + t] = lds[t] + lds[128 + t] + lds[256 + t] + lds[384 + t];
}

// ---------------------------------------------------------------- head MLP -> scalar (split-K)
__global__ void head_kernel(const float* __restrict__ colsum, const float* __restrict__ gf,
                            const float* __restrict__ W1, const float* __restrict__ b1,
                            const float* __restrict__ W2, const float* __restrict__ b2,
                            float* __restrict__ out) {
    __shared__ float h[448];
    __shared__ float sh[512];
    __shared__ float h1[64];
    int t = threadIdx.x;  // 512 threads
    if (t < 128) h[t] = colsum[t] * (1.0f / N_FM);
    else if (t < 256) h[t] = colsum[t] * (1.0f / N_TP);
    else if (t < 384) h[t] = colsum[t] * (1.0f / N_SM);
    else if (t < 448) h[t] = gf[t - 384];
    __syncthreads();
    {
        int col = t & 63, slice = t >> 6;
        float a = 0.0f;
        for (int k = slice * 56; k < slice * 56 + 56; k++) a += h[k] * W1[k * 64 + col];
        sh[slice * 64 + col] = a;
    }
    __syncthreads();
    if (t < 64) {
        float a = b1[t];
#pragma unroll
        for (int s = 0; s < 8; s++) a += sh[s * 64 + t];
        h1[t] = fmaxf(a, 0.0f);
    }
    __syncthreads();
    if (t < 64) {
        float p = h1[t] * W2[t];
#pragma unroll
        for (int off = 1; off < 64; off <<= 1) p += __shfl_xor(p, off);
        if (t == 0) out[0] = p + b2[0];
    }
}

extern "C" void kernel_launch(void* const* d_in, const int* in_sizes, int n_in,
                              void* d_out, int out_size, void* d_ws, size_t ws_size,
                              hipStream_t stream) {
    const float* x_fm = (const float*)d_in[0];
    const float* x_sm = (const float*)d_in[1];
    const float* period_vol = (const float*)d_in[2];
    const float* gf = (const float*)d_in[3];
    const float* pe_table = (const float*)d_in[4];
    const int* qoq_src = (const int*)d_in[5];
    const int* qoq_dst = (const int*)d_in[6];
    const int* bp_src = (const int*)d_in[7];
    const int* bp_dst = (const int*)d_in[8];
    const int* cp_src = (const int*)d_in[9];
    const int* cp_dst = (const int*)d_in[10];
    const int* cd_src = (const int*)d_in[11];
    const int* cd_dst = (const int*)d_in[12];
    const int* rb_src = (const int*)d_in[13];
    const int* rb_dst = (const int*)d_in[14];
    const float* qoq_Wl = (const float*)d_in[15];
    const float* qoq_bl = (const float*)d_in[16];
    const float* qoq_Wr = (const float*)d_in[17];
    const float* bp_Wl = (const float*)d_in[18];
    const float* bp_bl = (const float*)d_in[19];
    const float* bp_Wr = (const float*)d_in[20];
    const float* cp_Wl = (const float*)d_in[21];
    const float* cp_bl = (const float*)d_in[22];
    const float* cp_Wr = (const float*)d_in[23];
    const float* cd_Wl = (const float*)d_in[24];
    const float* cd_bl = (const float*)d_in[25];
    const float* cd_Wr = (const float*)d_in[26];
    const float* rb_Wl = (const float*)d_in[27];
    const float* rb_bl = (const float*)d_in[28];
    const float* rb_Wr = (const float*)d_in[29];
    const float* ln_fm_g = (const float*)d_in[30];
    const float* ln_fm_b = (const float*)d_in[31];
    const float* ln_tp_g = (const float*)d_in[32];
    const float* ln_tp_b = (const float*)d_in[33];
    const float* ln_sm_g = (const float*)d_in[34];
    const float* ln_sm_b = (const float*)d_in[35];
    const float* head_W1 = (const float*)d_in[36];
    const float* head_b1 = (const float*)d_in[37];
    const float* head_W2 = (const float*)d_in[38];
    const float* head_b2 = (const float*)d_in[39];

    // workspace (4-byte words); zero region: bucket cursors + colsum
    unsigned* wsu = (unsigned*)d_ws;
    size_t off = 0;
    int* bwork = (int*)(wsu + off); off += NBUCK;
    float* colsum = (float*)(wsu + off); off += 384;
    size_t zero_words = off;
    off = (off + 3) & ~(size_t)3;  // 16B-align everything downstream (uint4 loads)
    unsigned* pairs = wsu + off; off += PAIRS_CAP;
    int* so_all = (int*)(wsu + off); off += PAIRS_CAP;
    int* el_beg = (int*)(wsu + off); off += NTOT;
    int* el_end = (int*)(wsu + off); off += NTOT;
    unsigned* mean_qoq = wsu + off; off += (size_t)N_FM * 32;
    unsigned* mean_cp  = wsu + off; off += (size_t)N_FM * 16;
    unsigned* mean_rb  = wsu + off; off += (size_t)N_FM * 16;
    unsigned* mean_bp  = wsu + off; off += (size_t)N_TP * 32;
    unsigned* mean_cd  = wsu + off; off += (size_t)N_SM * 16;
    unsigned* pe_f     = wsu + off; off += (size_t)N_TP * 16;
    unsigned* x_fm_f   = wsu + off; off += (size_t)N_FM * 32;
    unsigned* x_sm_f   = wsu + off; off += (size_t)N_SM * 16;
    unsigned* wf_fm    = wsu + off; off += 12288;
    unsigned* wf_tp    = wsu + off; off += 6144;
    unsigned* wf_sm    = wsu + off; off += 4096;
    float* bias_fm     = (float*)(wsu + off); off += 128;

    // per-block column partials alias the (dead-after-esort) pairs buffer
    float* part_fm = (float*)pairs;                 // GRID_FM*128
    float* part_tp = part_fm + GRID_FM * 128;       // GRID_TP*128
    float* part_sm = part_tp + GRID_TP * 128;       // GRID_SM*128

    hipMemsetAsync(d_ws, 0, zero_words * 4, stream);

    pack_all<<<(R7 + 255) / 256, 256, 0, stream>>>(
        x_fm, x_sm, pe_table, period_vol, qoq_Wl, cp_Wl, rb_Wl, qoq_Wr, cp_Wr, rb_Wr,
        bp_Wl, bp_Wr, cd_Wl, cd_Wr, qoq_bl, cp_bl, rb_bl,
        x_fm_f, x_sm_f, pe_f, wf_fm, wf_tp, wf_sm, bias_fm);

    EdgePtrs EP{qoq_src, qoq_dst, cp_src, cp_dst, rb_src, rb_dst, bp_src, bp_dst, cd_src, cd_dst};

    bin_kernel<<<NCHUNK, 256, 0, stream>>>(EP, bwork, pairs);
    esort<<<NBUCK, 256, 0, stream>>>(bwork, pairs, so_all, el_beg, el_end);
    gather_all<<<(G5 + 255) / 256, 256, 0, stream>>>(el_beg, el_end, so_all, x_fm_f, pe_f,
                                                     mean_qoq, mean_cp, mean_rb, mean_bp, mean_cd);

    // MFMA row kernels (fused GEMM + LN + ReLU + per-block column partials)
    fm_mfma<<<GRID_FM, 256, 0, stream>>>(mean_qoq, mean_cp, mean_rb, x_fm_f, wf_fm,
                                         bias_fm, ln_fm_g, ln_fm_b, part_fm);
    rows_mfma<2, 1><<<GRID_TP, 256, 0, stream>>>(N_TP / 16, mean_bp, pe_f, wf_tp,
                                                 bp_bl, ln_tp_g, ln_tp_b, part_tp);
    rows_mfma<1, 1><<<GRID_SM, 256, 0, stream>>>(N_SM / 16, mean_cd, x_sm_f, wf_sm,
                                                 cd_bl, ln_sm_g, ln_sm_b, part_sm);

    reduce_cols<<<3, 512, 0, stream>>>(part_fm, colsum);

    head_kernel<<<1, 512, 0, stream>>>(colsum, gf, head_W1, head_b1, head_W2, head_b2,
                                       (float*)d_out);
}